// Round 6
// baseline (296.463 us; speedup 1.0000x reference)
//
#include <hip/hip_runtime.h>
#include <hip/hip_fp16.h>

// 2-layer GCN, pull-based CSR aggregation. fp32 math, fp16 intermediates.
// CSR build WITHOUT per-node atomics (R5 showed device-atomic throughput
// ~6/cyc caps fill_adj at 55us regardless of occupancy):
//   K1: bucket edges by dst>>8 into 196 fixed-capacity buckets (atomics on
//       196 line-padded counters only), payload packed (low8<<24 | src).
//   K2: per-bucket LDS counting sort by low byte -> rowstart, dinv, and a
//       contiguous coalesced adj write. Row-internal order is arbitrary
//       (sum commutative).
// Then gemm1 -> agg1(+bias,relu,residual) -> gemm2 -> agg2 -> d_out.

#define FDIM 128
#define GK 32
#define CAP 6144   // bucket capacity; E/196 ~ 4082 expected, +32 sigma margin

// ---- K1: bucket scatter ----
__global__ void bucket_scatter_kernel(const int* __restrict__ ei, int E,
                                      int* __restrict__ bcntp, unsigned* __restrict__ bucket) {
    int e = blockIdx.x * blockDim.x + threadIdx.x;
    if (e >= E) return;
    int src = ei[e];
    int dst = ei[E + e];
    int b = dst >> 8;
    int pos = atomicAdd(&bcntp[b << 4], 1);   // stride-16 ints = 1 counter per 64B line
    if (pos < CAP)
        bucket[(size_t)b * CAP + pos] = ((unsigned)(dst & 255) << 24) | (unsigned)src;
}

// ---- K2: per-bucket counting sort -> CSR ----
__global__ void bucket_csr_kernel(const int* __restrict__ bcntp, const unsigned* __restrict__ bucket,
                                  int* __restrict__ adj, int* __restrict__ rowstart,
                                  float* __restrict__ dinv, int N, int nbk) {
    __shared__ int sbuf[256];
    __shared__ int hist[256];
    __shared__ int cur[256];
    int b = blockIdx.x, t = threadIdx.x;

    // redundant per-block scan of bucket counts (nbk <= 256) -> global bases
    int cnt_t = (t < nbk) ? min(bcntp[t << 4], CAP) : 0;
    sbuf[t] = cnt_t;
    __syncthreads();
    for (int off = 1; off < 256; off <<= 1) {
        int v = (t >= off) ? sbuf[t - off] : 0;
        __syncthreads();
        sbuf[t] += v;
        __syncthreads();
    }
    int bb = (b == 0) ? 0 : sbuf[b - 1];   // this bucket's base in adj
    int nb = sbuf[b] - bb;                 // this bucket's count
    int total = sbuf[nbk - 1];             // == E (no overflow)

    hist[t] = 0;
    __syncthreads();
    const unsigned* bk = bucket + (size_t)b * CAP;
    for (int e = t; e < nb; e += 256) atomicAdd(&hist[bk[e] >> 24], 1);
    __syncthreads();
    int h_t = hist[t];
    sbuf[t] = h_t;
    __syncthreads();
    for (int off = 1; off < 256; off <<= 1) {
        int v = (t >= off) ? sbuf[t - off] : 0;
        __syncthreads();
        sbuf[t] += v;
        __syncthreads();
    }
    int excl_t = sbuf[t] - h_t;

    int node = b * 256 + t;
    if (node < N) {
        rowstart[node] = bb + excl_t;
        dinv[node] = rsqrtf((float)(h_t + 1));   // +1 self-loop
    }
    if (b == 0 && t == 0) rowstart[N] = total;

    cur[t] = excl_t;
    __syncthreads();
    for (int e = t; e < nb; e += 256) {
        unsigned v = bk[e];
        int pos = atomicAdd(&cur[v >> 24], 1);   // LDS atomic, cheap
        adj[bb + pos] = (int)(v & 0xFFFFFFu);    // src < 2^24
    }
}

// ---- tiled GEMM1: h1 = x @ W1 (fp16 out), 128x128 block, 8x8/thread ----
__launch_bounds__(256, 2)
__global__ void gemm1_tiled(const float* __restrict__ x, const float* __restrict__ W,
                            __half* __restrict__ h, int N) {
    __shared__ float Ws[GK][128];
    __shared__ float xs[GK][132];
    int t = threadIdx.x;
    int tx = t & 15, ty = t >> 4;
    int i0 = blockIdx.x * 128;

    float acc[8][8];
#pragma unroll
    for (int a = 0; a < 8; ++a)
#pragma unroll
        for (int b = 0; b < 8; ++b) acc[a][b] = 0.f;

    for (int kb = 0; kb < FDIM / GK; ++kb) {
        __syncthreads();
        for (int p = t; p < 1024; p += 256) {
            float4 v = *(const float4*)(W + (size_t)(kb * GK + (p >> 5)) * 128 + ((p & 31) * 4));
            *(float4*)&Ws[p >> 5][(p & 31) * 4] = v;
        }
        int kq = (t & 7) * 4;
        int rb = t >> 3;
#pragma unroll
        for (int pass = 0; pass < 4; ++pass) {
            int r = pass * 32 + rb;
            int row = i0 + r;
            float4 v = make_float4(0.f, 0.f, 0.f, 0.f);
            if (row < N) v = *(const float4*)(x + (size_t)row * FDIM + kb * GK + kq);
            xs[kq + 0][r] = v.x;
            xs[kq + 1][r] = v.y;
            xs[kq + 2][r] = v.z;
            xs[kq + 3][r] = v.w;
        }
        __syncthreads();
#pragma unroll 4
        for (int k = 0; k < GK; ++k) {
            float4 a0 = *(const float4*)&xs[k][ty * 4];
            float4 a1 = *(const float4*)&xs[k][64 + ty * 4];
            float4 b0 = *(const float4*)&Ws[k][tx * 4];
            float4 b1 = *(const float4*)&Ws[k][64 + tx * 4];
            float av[8] = {a0.x, a0.y, a0.z, a0.w, a1.x, a1.y, a1.z, a1.w};
            float bv[8] = {b0.x, b0.y, b0.z, b0.w, b1.x, b1.y, b1.z, b1.w};
#pragma unroll
            for (int a = 0; a < 8; ++a)
#pragma unroll
                for (int b = 0; b < 8; ++b) acc[a][b] += av[a] * bv[b];
        }
    }
#pragma unroll
    for (int g = 0; g < 2; ++g)
#pragma unroll
        for (int a = 0; a < 4; ++a) {
            int row = i0 + g * 64 + ty * 4 + a;
            if (row < N) {
                int ri = g * 4 + a;
                union { __half2 hh[2]; float2 f; } u0, u1;
                u0.hh[0] = __floats2half2_rn(acc[ri][0], acc[ri][1]);
                u0.hh[1] = __floats2half2_rn(acc[ri][2], acc[ri][3]);
                u1.hh[0] = __floats2half2_rn(acc[ri][4], acc[ri][5]);
                u1.hh[1] = __floats2half2_rn(acc[ri][6], acc[ri][7]);
                *(float2*)(h + (size_t)row * FDIM + tx * 4) = u0.f;
                *(float2*)(h + (size_t)row * FDIM + 64 + tx * 4) = u1.f;
            }
        }
}

// z[i,:] = relu( dinv[i]*(sum_s h1[s,:]*dinv[s] + h1[i,:]*dinv[i]) + b1 ) + x[i,:]
__global__ void agg1_kernel(const __half* __restrict__ h1, const int* __restrict__ rowstart,
                            const int* __restrict__ adj, const float* __restrict__ dinv,
                            const float* __restrict__ x, const float* __restrict__ b1,
                            __half* __restrict__ z, int N) {
    int wave = threadIdx.x >> 6;
    int lane = threadIdx.x & 63;
    int i = blockIdx.x * 4 + wave;
    if (i >= N) return;
    int s0 = rowstart[i], s1 = rowstart[i + 1];
    float ax = 0.f, ay = 0.f;
    int n = s0;
    for (; n + 7 < s1; n += 8) {
        int s[8];
        float w[8];
        float2 r[8];
#pragma unroll
        for (int q = 0; q < 8; ++q) s[q] = adj[n + q];
#pragma unroll
        for (int q = 0; q < 8; ++q) w[q] = dinv[s[q]];
#pragma unroll
        for (int q = 0; q < 8; ++q)
            r[q] = __half22float2(((const __half2*)(h1 + (size_t)s[q] * FDIM))[lane]);
#pragma unroll
        for (int q = 0; q < 8; ++q) {
            ax += r[q].x * w[q];
            ay += r[q].y * w[q];
        }
    }
    for (; n < s1; ++n) {
        int sa = adj[n];
        float wa = dinv[sa];
        float2 ra = __half22float2(((const __half2*)(h1 + (size_t)sa * FDIM))[lane]);
        ax += ra.x * wa;
        ay += ra.y * wa;
    }
    float di = dinv[i];
    float self = di * di;
    float2 hi = __half22float2(((const __half2*)(h1 + (size_t)i * FDIM))[lane]);
    ax = ax * di + hi.x * self;
    ay = ay * di + hi.y * self;
    float2 bb = ((const float2*)b1)[lane];
    float2 xi = ((const float2*)(x + (size_t)i * FDIM))[lane];
    float rx = fmaxf(ax + bb.x, 0.f) + xi.x;
    float ry = fmaxf(ay + bb.y, 0.f) + xi.y;
    ((__half2*)(z + (size_t)i * FDIM))[lane] = __floats2half2_rn(rx, ry);
}

// ---- tiled GEMM2: h2 = z @ W2 (fp16 in, fp16 out, dense stride 40) ----
__launch_bounds__(256, 2)
__global__ void gemm2_tiled(const __half* __restrict__ z, const float* __restrict__ W2,
                            __half* __restrict__ h2, int N) {
    __shared__ float Ws[GK][64];
    __shared__ float zs[GK][132];
    int t = threadIdx.x;
    int tx = t & 15, ty = t >> 4;
    int i0 = blockIdx.x * 128;

    float acc[8][4];
#pragma unroll
    for (int a = 0; a < 8; ++a)
#pragma unroll
        for (int b = 0; b < 4; ++b) acc[a][b] = 0.f;

    for (int kb = 0; kb < FDIM / GK; ++kb) {
        __syncthreads();
        for (int p = t; p < GK * 64; p += 256) {
            int k = p >> 6, j = p & 63;
            Ws[k][j] = (j < 40) ? W2[(size_t)(kb * GK + k) * 40 + j] : 0.f;
        }
        int kq = (t & 3) * 8;
        int rb = t >> 2;
#pragma unroll
        for (int pass = 0; pass < 2; ++pass) {
            int r = pass * 64 + rb;
            int row = i0 + r;
            union { float4 v; __half2 hh[4]; } u;
            u.v = make_float4(0.f, 0.f, 0.f, 0.f);
            if (row < N) u.v = *(const float4*)(z + (size_t)row * FDIM + kb * GK + kq);
#pragma unroll
            for (int j = 0; j < 4; ++j) {
                float2 f = __half22float2(u.hh[j]);
                zs[kq + 2 * j][r] = f.x;
                zs[kq + 2 * j + 1][r] = f.y;
            }
        }
        __syncthreads();
#pragma unroll 4
        for (int k = 0; k < GK; ++k) {
            float4 a0 = *(const float4*)&zs[k][ty * 4];
            float4 a1 = *(const float4*)&zs[k][64 + ty * 4];
            float4 b0 = *(const float4*)&Ws[k][tx * 4];
            float av[8] = {a0.x, a0.y, a0.z, a0.w, a1.x, a1.y, a1.z, a1.w};
            float bv[4] = {b0.x, b0.y, b0.z, b0.w};
#pragma unroll
            for (int a = 0; a < 8; ++a)
#pragma unroll
                for (int b = 0; b < 4; ++b) acc[a][b] += av[a] * bv[b];
        }
    }
    if (tx < 10) {
#pragma unroll
        for (int g = 0; g < 2; ++g)
#pragma unroll
            for (int a = 0; a < 4; ++a) {
                int row = i0 + g * 64 + ty * 4 + a;
                if (row < N) {
                    int ri = g * 4 + a;
                    union { __half2 hh[2]; float2 f; } u;
                    u.hh[0] = __floats2half2_rn(acc[ri][0], acc[ri][1]);
                    u.hh[1] = __floats2half2_rn(acc[ri][2], acc[ri][3]);
                    *(float2*)(h2 + (size_t)row * 40 + tx * 4) = u.f;
                }
            }
    }
}

// y[i,:] = dinv[i]*(sum_s h2[s,:]*dinv[s] + h2[i,:]*dinv[i]) + b2
__global__ void agg2_kernel(const __half* __restrict__ h2, const int* __restrict__ rowstart,
                            const int* __restrict__ adj, const float* __restrict__ dinv,
                            const float* __restrict__ b2, float* __restrict__ y, int N) {
    int wave = threadIdx.x >> 6;
    int lane = threadIdx.x & 63;
    int i = blockIdx.x * 4 + wave;
    if (i >= N) return;
    int e = (lane >= 40) ? 2 : ((lane >= 20) ? 1 : 0);
    int f = lane - 20 * e;
    int s0 = rowstart[i], s1 = rowstart[i + 1];
    float ax = 0.f, ay = 0.f;
    if (lane < 60) {
        int n = s0 + e;
        for (; n + 9 < s1; n += 12) {
            int s[4];
            float w[4];
            float2 r[4];
#pragma unroll
            for (int q = 0; q < 4; ++q) s[q] = adj[n + 3 * q];
#pragma unroll
            for (int q = 0; q < 4; ++q) w[q] = dinv[s[q]];
#pragma unroll
            for (int q = 0; q < 4; ++q)
                r[q] = __half22float2(((const __half2*)(h2 + (size_t)s[q] * 40))[f]);
#pragma unroll
            for (int q = 0; q < 4; ++q) {
                ax += r[q].x * w[q];
                ay += r[q].y * w[q];
            }
        }
        for (; n < s1; n += 3) {
            int sa = adj[n];
            float wa = dinv[sa];
            float2 ra = __half22float2(((const __half2*)(h2 + (size_t)sa * 40))[f]);
            ax += ra.x * wa;
            ay += ra.y * wa;
        }
    }
    float sx = ax + __shfl(ax, lane + 20, 64) + __shfl(ax, lane + 40, 64);
    float sy = ay + __shfl(ay, lane + 20, 64) + __shfl(ay, lane + 40, 64);
    if (lane < 20) {
        float di = dinv[i];
        float2 hi = __half22float2(((const __half2*)(h2 + (size_t)i * 40))[lane]);
        float2 bb = ((const float2*)b2)[lane];
        float2 res;
        res.x = sx * di + hi.x * di * di + bb.x;
        res.y = sy * di + hi.y * di * di + bb.y;
        ((float2*)(y + (size_t)i * 40))[lane] = res;
    }
}

extern "C" void kernel_launch(void* const* d_in, const int* in_sizes, int n_in,
                              void* d_out, int out_size, void* d_ws, size_t ws_size,
                              hipStream_t stream) {
    const float* x  = (const float*)d_in[0];
    const int*   ei = (const int*)d_in[1];
    const float* W1 = (const float*)d_in[2];
    const float* b1 = (const float*)d_in[3];
    const float* W2 = (const float*)d_in[4];
    const float* b2 = (const float*)d_in[5];
    float* y = (float*)d_out;

    const int H = in_sizes[3];           // 128
    const int F = in_sizes[2] / H;       // 128
    const int N = in_sizes[0] / F;       // 50000
    const int E = in_sizes[1] / 2;       // 800000
    (void)H; (void)ws_size; (void)n_in; (void)out_size;

    const int nbk = (N + 255) >> 8;      // 196 buckets (must be <= 256)

    size_t off = 0;
    auto carve = [&](size_t bytes) -> void* {
        void* p = (char*)d_ws + off;
        off += (bytes + 255) & ~(size_t)255;
        return p;
    };
    int*      bcntp    = (int*)carve((size_t)nbk * 16 * 4);        // 1 counter / 64B line
    unsigned* bucket   = (unsigned*)carve((size_t)nbk * CAP * 4);  // ~4.8 MB
    int*      rowstart = (int*)carve((size_t)(N + 1) * 4);
    float*    dinv     = (float*)carve((size_t)N * 4);
    int*      adj      = (int*)carve((size_t)E * 4);
    __half*   h1       = (__half*)carve((size_t)N * FDIM * 2);
    __half*   z        = (__half*)carve((size_t)N * FDIM * 2);
    __half*   h2       = h1;   // h1 dead after agg1; h2 = N x 40 fp16 (fits)

    hipMemsetAsync(bcntp, 0, (size_t)nbk * 16 * 4, stream);

    int eb = (E + 255) / 256;
    bucket_scatter_kernel<<<eb, 256, 0, stream>>>(ei, E, bcntp, bucket);
    bucket_csr_kernel<<<nbk, 256, 0, stream>>>(bcntp, bucket, adj, rowstart, dinv, N, nbk);

    int nbt = (N + 127) / 128;
    gemm1_tiled<<<nbt, 256, 0, stream>>>(x, W1, h1, N);
    agg1_kernel<<<(N + 3) / 4, 256, 0, stream>>>(h1, rowstart, adj, dinv, x, b1, z, N);
    gemm2_tiled<<<nbt, 256, 0, stream>>>(z, W2, h2, N);
    agg2_kernel<<<(N + 3) / 4, 256, 0, stream>>>(h2, rowstart, adj, dinv, b2, y, N);
}

// Round 7
// 278.700 us; speedup vs baseline: 1.0637x; 1.0637x over previous
//
#include <hip/hip_runtime.h>
#include <hip/hip_fp16.h>

// 2-layer GCN, pull-based CSR aggregation. fp32 math, fp16 intermediates.
// CSR build with ZERO global atomics (R5/R6 measured device atomics cap at
// ~6/cyc -> >=55us for 800K atomics regardless of address distribution):
//   K_hist:    per-2048-edge-chunk LDS histogram of dst>>8 -> histT[bkt][chunk]
//   K_scan_tot: bucket totals -> exclusive base[nbk], base[nbk]=E
//   K_offsets: per-bucket exclusive scan over chunks (+base) in-place
//   K_scatter: re-read chunk, pos from LDS counters seeded with exact offsets,
//              write packed (dst&255)<<24|src  (no CAP, no overflow)
//   K_csr:     per-bucket LDS counting sort by low byte -> rowstart/dinv/adj
// Then gemm1 -> agg1(+bias,relu,residual) -> gemm2 -> agg2 -> d_out.

#define FDIM 128
#define GK 32
#define CHUNK 2048   // edges per chunk; nchunks = ceil(E/CHUNK) must be <= 512

__global__ void hist_kernel(const int* __restrict__ dst, int E, int nchunks, int nbk,
                            int* __restrict__ histT) {
    __shared__ int hist[256];
    int j = blockIdx.x, t = threadIdx.x;
    hist[t] = 0;
    __syncthreads();
    int base = j * CHUNK;
#pragma unroll
    for (int k = 0; k < CHUNK / 256; ++k) {
        int e = base + k * 256 + t;
        if (e < E) atomicAdd(&hist[dst[e] >> 8], 1);
    }
    __syncthreads();
    if (t < nbk) histT[t * nchunks + j] = hist[t];
}

__global__ void scan_tot_kernel(const int* __restrict__ histT, int nchunks, int nbk,
                                int* __restrict__ base_) {
    __shared__ int s[256];
    int t = threadIdx.x;
    int tot = 0;
    if (t < nbk) {
        const int* row = histT + (size_t)t * nchunks;
        for (int j = 0; j < nchunks; ++j) tot += row[j];
    }
    s[t] = tot;
    __syncthreads();
    for (int off = 1; off < 256; off <<= 1) {
        int v = (t >= off) ? s[t - off] : 0;
        __syncthreads();
        s[t] += v;
        __syncthreads();
    }
    if (t < nbk) base_[t] = s[t] - tot;
    if (t == 0) base_[nbk] = s[255];   // total = E
}

__global__ void offsets_kernel(int* __restrict__ histT, int nchunks, 
                               const int* __restrict__ base_) {
    __shared__ int s[512];
    int b = blockIdx.x, t = threadIdx.x;
    int* row = histT + (size_t)b * nchunks;
    int v = (t < nchunks) ? row[t] : 0;
    s[t] = v;
    __syncthreads();
    for (int off = 1; off < 512; off <<= 1) {
        int tv = (t >= off) ? s[t - off] : 0;
        __syncthreads();
        s[t] += tv;
        __syncthreads();
    }
    if (t < nchunks) row[t] = base_[b] + s[t] - v;   // exact scatter base
}

__global__ void scatter_kernel(const int* __restrict__ ei, int E, int nchunks, int nbk,
                               const int* __restrict__ histT, unsigned* __restrict__ bkt) {
    __shared__ int cur[256];
    int j = blockIdx.x, t = threadIdx.x;
    if (t < nbk) cur[t] = histT[t * nchunks + j];
    __syncthreads();
    int base = j * CHUNK;
#pragma unroll
    for (int k = 0; k < CHUNK / 256; ++k) {
        int e = base + k * 256 + t;
        if (e < E) {
            int src = ei[e];
            int d = ei[E + e];
            int pos = atomicAdd(&cur[d >> 8], 1);   // LDS atomic
            bkt[pos] = ((unsigned)(d & 255) << 24) | (unsigned)src;
        }
    }
}

__global__ void csr_kernel(const int* __restrict__ base_, const unsigned* __restrict__ bkt,
                           int* __restrict__ adj, int* __restrict__ rowstart,
                           float* __restrict__ dinv, int N, int nbk) {
    __shared__ int sbuf[256];
    __shared__ int hist[256];
    __shared__ int cur[256];
    int b = blockIdx.x, t = threadIdx.x;
    int bb = base_[b];
    int nb = base_[b + 1] - bb;
    hist[t] = 0;
    __syncthreads();
    const unsigned* bk = bkt + bb;
    for (int e = t; e < nb; e += 256) atomicAdd(&hist[bk[e] >> 24], 1);
    __syncthreads();
    int h_t = hist[t];
    sbuf[t] = h_t;
    __syncthreads();
    for (int off = 1; off < 256; off <<= 1) {
        int v = (t >= off) ? sbuf[t - off] : 0;
        __syncthreads();
        sbuf[t] += v;
        __syncthreads();
    }
    int excl_t = sbuf[t] - h_t;
    int node = b * 256 + t;
    if (node < N) {
        rowstart[node] = bb + excl_t;
        dinv[node] = rsqrtf((float)(h_t + 1));   // +1 self-loop
    }
    if (b == 0 && t == 0) rowstart[N] = base_[nbk];
    cur[t] = excl_t;
    __syncthreads();
    for (int e = t; e < nb; e += 256) {
        unsigned v = bk[e];
        int pos = atomicAdd(&cur[v >> 24], 1);   // LDS atomic
        adj[bb + pos] = (int)(v & 0xFFFFFFu);    // src < 2^24
    }
}

// ---- tiled GEMM1: h1 = x @ W1 (fp16 out), 128x128 block, 8x8/thread ----
__launch_bounds__(256, 2)
__global__ void gemm1_tiled(const float* __restrict__ x, const float* __restrict__ W,
                            __half* __restrict__ h, int N) {
    __shared__ float Ws[GK][128];
    __shared__ float xs[GK][132];
    int t = threadIdx.x;
    int tx = t & 15, ty = t >> 4;
    int i0 = blockIdx.x * 128;

    float acc[8][8];
#pragma unroll
    for (int a = 0; a < 8; ++a)
#pragma unroll
        for (int b = 0; b < 8; ++b) acc[a][b] = 0.f;

    for (int kb = 0; kb < FDIM / GK; ++kb) {
        __syncthreads();
        for (int p = t; p < 1024; p += 256) {
            float4 v = *(const float4*)(W + (size_t)(kb * GK + (p >> 5)) * 128 + ((p & 31) * 4));
            *(float4*)&Ws[p >> 5][(p & 31) * 4] = v;
        }
        int kq = (t & 7) * 4;
        int rb = t >> 3;
#pragma unroll
        for (int pass = 0; pass < 4; ++pass) {
            int r = pass * 32 + rb;
            int row = i0 + r;
            float4 v = make_float4(0.f, 0.f, 0.f, 0.f);
            if (row < N) v = *(const float4*)(x + (size_t)row * FDIM + kb * GK + kq);
            xs[kq + 0][r] = v.x;
            xs[kq + 1][r] = v.y;
            xs[kq + 2][r] = v.z;
            xs[kq + 3][r] = v.w;
        }
        __syncthreads();
#pragma unroll 4
        for (int k = 0; k < GK; ++k) {
            float4 a0 = *(const float4*)&xs[k][ty * 4];
            float4 a1 = *(const float4*)&xs[k][64 + ty * 4];
            float4 b0 = *(const float4*)&Ws[k][tx * 4];
            float4 b1 = *(const float4*)&Ws[k][64 + tx * 4];
            float av[8] = {a0.x, a0.y, a0.z, a0.w, a1.x, a1.y, a1.z, a1.w};
            float bv[8] = {b0.x, b0.y, b0.z, b0.w, b1.x, b1.y, b1.z, b1.w};
#pragma unroll
            for (int a = 0; a < 8; ++a)
#pragma unroll
                for (int b = 0; b < 8; ++b) acc[a][b] += av[a] * bv[b];
        }
    }
#pragma unroll
    for (int g = 0; g < 2; ++g)
#pragma unroll
        for (int a = 0; a < 4; ++a) {
            int row = i0 + g * 64 + ty * 4 + a;
            if (row < N) {
                int ri = g * 4 + a;
                union { __half2 hh[2]; float2 f; } u0, u1;
                u0.hh[0] = __floats2half2_rn(acc[ri][0], acc[ri][1]);
                u0.hh[1] = __floats2half2_rn(acc[ri][2], acc[ri][3]);
                u1.hh[0] = __floats2half2_rn(acc[ri][4], acc[ri][5]);
                u1.hh[1] = __floats2half2_rn(acc[ri][6], acc[ri][7]);
                *(float2*)(h + (size_t)row * FDIM + tx * 4) = u0.f;
                *(float2*)(h + (size_t)row * FDIM + 64 + tx * 4) = u1.f;
            }
        }
}

// z[i,:] = relu( dinv[i]*(sum_s h1[s,:]*dinv[s] + h1[i,:]*dinv[i]) + b1 ) + x[i,:]
__global__ void agg1_kernel(const __half* __restrict__ h1, const int* __restrict__ rowstart,
                            const int* __restrict__ adj, const float* __restrict__ dinv,
                            const float* __restrict__ x, const float* __restrict__ b1,
                            __half* __restrict__ z, int N) {
    int wave = threadIdx.x >> 6;
    int lane = threadIdx.x & 63;
    int i = blockIdx.x * 4 + wave;
    if (i >= N) return;
    int s0 = rowstart[i], s1 = rowstart[i + 1];
    float ax = 0.f, ay = 0.f;
    int n = s0;
    for (; n + 7 < s1; n += 8) {
        int s[8];
        float w[8];
        float2 r[8];
#pragma unroll
        for (int q = 0; q < 8; ++q) s[q] = adj[n + q];
#pragma unroll
        for (int q = 0; q < 8; ++q) w[q] = dinv[s[q]];
#pragma unroll
        for (int q = 0; q < 8; ++q)
            r[q] = __half22float2(((const __half2*)(h1 + (size_t)s[q] * FDIM))[lane]);
#pragma unroll
        for (int q = 0; q < 8; ++q) {
            ax += r[q].x * w[q];
            ay += r[q].y * w[q];
        }
    }
    for (; n < s1; ++n) {
        int sa = adj[n];
        float wa = dinv[sa];
        float2 ra = __half22float2(((const __half2*)(h1 + (size_t)sa * FDIM))[lane]);
        ax += ra.x * wa;
        ay += ra.y * wa;
    }
    float di = dinv[i];
    float self = di * di;
    float2 hi = __half22float2(((const __half2*)(h1 + (size_t)i * FDIM))[lane]);
    ax = ax * di + hi.x * self;
    ay = ay * di + hi.y * self;
    float2 bb = ((const float2*)b1)[lane];
    float2 xi = ((const float2*)(x + (size_t)i * FDIM))[lane];
    float rx = fmaxf(ax + bb.x, 0.f) + xi.x;
    float ry = fmaxf(ay + bb.y, 0.f) + xi.y;
    ((__half2*)(z + (size_t)i * FDIM))[lane] = __floats2half2_rn(rx, ry);
}

// ---- tiled GEMM2: h2 = z @ W2 (fp16 in, fp16 out, dense stride 40) ----
__launch_bounds__(256, 2)
__global__ void gemm2_tiled(const __half* __restrict__ z, const float* __restrict__ W2,
                            __half* __restrict__ h2, int N) {
    __shared__ float Ws[GK][64];
    __shared__ float zs[GK][132];
    int t = threadIdx.x;
    int tx = t & 15, ty = t >> 4;
    int i0 = blockIdx.x * 128;

    float acc[8][4];
#pragma unroll
    for (int a = 0; a < 8; ++a)
#pragma unroll
        for (int b = 0; b < 4; ++b) acc[a][b] = 0.f;

    for (int kb = 0; kb < FDIM / GK; ++kb) {
        __syncthreads();
        for (int p = t; p < GK * 64; p += 256) {
            int k = p >> 6, j = p & 63;
            Ws[k][j] = (j < 40) ? W2[(size_t)(kb * GK + k) * 40 + j] : 0.f;
        }
        int kq = (t & 3) * 8;
        int rb = t >> 2;
#pragma unroll
        for (int pass = 0; pass < 2; ++pass) {
            int r = pass * 64 + rb;
            int row = i0 + r;
            union { float4 v; __half2 hh[4]; } u;
            u.v = make_float4(0.f, 0.f, 0.f, 0.f);
            if (row < N) u.v = *(const float4*)(z + (size_t)row * FDIM + kb * GK + kq);
#pragma unroll
            for (int j = 0; j < 4; ++j) {
                float2 f = __half22float2(u.hh[j]);
                zs[kq + 2 * j][r] = f.x;
                zs[kq + 2 * j + 1][r] = f.y;
            }
        }
        __syncthreads();
#pragma unroll 4
        for (int k = 0; k < GK; ++k) {
            float4 a0 = *(const float4*)&zs[k][ty * 4];
            float4 a1 = *(const float4*)&zs[k][64 + ty * 4];
            float4 b0 = *(const float4*)&Ws[k][tx * 4];
            float av[8] = {a0.x, a0.y, a0.z, a0.w, a1.x, a1.y, a1.z, a1.w};
            float bv[4] = {b0.x, b0.y, b0.z, b0.w};
#pragma unroll
            for (int a = 0; a < 8; ++a)
#pragma unroll
                for (int b = 0; b < 4; ++b) acc[a][b] += av[a] * bv[b];
        }
    }
    if (tx < 10) {
#pragma unroll
        for (int g = 0; g < 2; ++g)
#pragma unroll
            for (int a = 0; a < 4; ++a) {
                int row = i0 + g * 64 + ty * 4 + a;
                if (row < N) {
                    int ri = g * 4 + a;
                    union { __half2 hh[2]; float2 f; } u;
                    u.hh[0] = __floats2half2_rn(acc[ri][0], acc[ri][1]);
                    u.hh[1] = __floats2half2_rn(acc[ri][2], acc[ri][3]);
                    *(float2*)(h2 + (size_t)row * 40 + tx * 4) = u.f;
                }
            }
    }
}

// y[i,:] = dinv[i]*(sum_s h2[s,:]*dinv[s] + h2[i,:]*dinv[i]) + b2
__global__ void agg2_kernel(const __half* __restrict__ h2, const int* __restrict__ rowstart,
                            const int* __restrict__ adj, const float* __restrict__ dinv,
                            const float* __restrict__ b2, float* __restrict__ y, int N) {
    int wave = threadIdx.x >> 6;
    int lane = threadIdx.x & 63;
    int i = blockIdx.x * 4 + wave;
    if (i >= N) return;
    int e = (lane >= 40) ? 2 : ((lane >= 20) ? 1 : 0);
    int f = lane - 20 * e;
    int s0 = rowstart[i], s1 = rowstart[i + 1];
    float ax = 0.f, ay = 0.f;
    if (lane < 60) {
        int n = s0 + e;
        for (; n + 9 < s1; n += 12) {
            int s[4];
            float w[4];
            float2 r[4];
#pragma unroll
            for (int q = 0; q < 4; ++q) s[q] = adj[n + 3 * q];
#pragma unroll
            for (int q = 0; q < 4; ++q) w[q] = dinv[s[q]];
#pragma unroll
            for (int q = 0; q < 4; ++q)
                r[q] = __half22float2(((const __half2*)(h2 + (size_t)s[q] * 40))[f]);
#pragma unroll
            for (int q = 0; q < 4; ++q) {
                ax += r[q].x * w[q];
                ay += r[q].y * w[q];
            }
        }
        for (; n < s1; n += 3) {
            int sa = adj[n];
            float wa = dinv[sa];
            float2 ra = __half22float2(((const __half2*)(h2 + (size_t)sa * 40))[f]);
            ax += ra.x * wa;
            ay += ra.y * wa;
        }
    }
    float sx = ax + __shfl(ax, lane + 20, 64) + __shfl(ax, lane + 40, 64);
    float sy = ay + __shfl(ay, lane + 20, 64) + __shfl(ay, lane + 40, 64);
    if (lane < 20) {
        float di = dinv[i];
        float2 hi = __half22float2(((const __half2*)(h2 + (size_t)i * 40))[lane]);
        float2 bb = ((const float2*)b2)[lane];
        float2 res;
        res.x = sx * di + hi.x * di * di + bb.x;
        res.y = sy * di + hi.y * di * di + bb.y;
        ((float2*)(y + (size_t)i * 40))[lane] = res;
    }
}

extern "C" void kernel_launch(void* const* d_in, const int* in_sizes, int n_in,
                              void* d_out, int out_size, void* d_ws, size_t ws_size,
                              hipStream_t stream) {
    const float* x  = (const float*)d_in[0];
    const int*   ei = (const int*)d_in[1];
    const float* W1 = (const float*)d_in[2];
    const float* b1 = (const float*)d_in[3];
    const float* W2 = (const float*)d_in[4];
    const float* b2 = (const float*)d_in[5];
    float* y = (float*)d_out;

    const int H = in_sizes[3];           // 128
    const int F = in_sizes[2] / H;       // 128
    const int N = in_sizes[0] / F;       // 50000
    const int E = in_sizes[1] / 2;       // 800000
    (void)H; (void)ws_size; (void)n_in; (void)out_size;

    const int nbk = (N + 255) >> 8;            // 196 buckets (<=256)
    const int nchunks = (E + CHUNK - 1) / CHUNK; // 391 (<=512)

    size_t off = 0;
    auto carve = [&](size_t bytes) -> void* {
        void* p = (char*)d_ws + off;
        off += (bytes + 255) & ~(size_t)255;
        return p;
    };
    int*      histT    = (int*)carve((size_t)nbk * nchunks * 4);
    int*      base_    = (int*)carve((size_t)(nbk + 1) * 4);
    unsigned* bkt      = (unsigned*)carve((size_t)E * 4);
    int*      rowstart = (int*)carve((size_t)(N + 1) * 4);
    float*    dinv     = (float*)carve((size_t)N * 4);
    int*      adj      = (int*)carve((size_t)E * 4);
    __half*   h1       = (__half*)carve((size_t)N * FDIM * 2);
    __half*   z        = (__half*)carve((size_t)N * FDIM * 2);
    __half*   h2       = h1;   // h1 dead after agg1; h2 = N x 40 fp16 (fits)

    hist_kernel<<<nchunks, 256, 0, stream>>>(ei + E, E, nchunks, nbk, histT);
    scan_tot_kernel<<<1, 256, 0, stream>>>(histT, nchunks, nbk, base_);
    offsets_kernel<<<nbk, 512, 0, stream>>>(histT, nchunks, base_);
    scatter_kernel<<<nchunks, 256, 0, stream>>>(ei, E, nchunks, nbk, histT, bkt);
    csr_kernel<<<nbk, 256, 0, stream>>>(base_, bkt, adj, rowstart, dinv, N, nbk);

    int nbt = (N + 127) / 128;
    gemm1_tiled<<<nbt, 256, 0, stream>>>(x, W1, h1, N);
    agg1_kernel<<<(N + 3) / 4, 256, 0, stream>>>(h1, rowstart, adj, dinv, x, b1, z, N);
    gemm2_tiled<<<nbt, 256, 0, stream>>>(z, W2, h2, N);
    agg2_kernel<<<(N + 3) / 4, 256, 0, stream>>>(h2, rowstart, adj, dinv, b2, y, N);
}

// Round 8
// 232.460 us; speedup vs baseline: 1.2753x; 1.1989x over previous
//
#include <hip/hip_runtime.h>
#include <hip/hip_fp16.h>

// 2-layer GCN, pull-based CSR aggregation. fp32 math, fp16 intermediates.
// CSR build with ZERO global atomics:
//   K_hist:    per-2048-edge-chunk LDS histogram of dst>>8 -> histT[bkt][chunk]
//   K_offsets: per-bucket exclusive scan over chunks (bucket-LOCAL) + tot[b]
//   K_base:    1-block scan of tot[nbk] -> base_[b], base_[nbk]=E  (tiny)
//   K_scatter: LDS cursors = base_[b] + local offset; packed (dst&255)<<24|src
//   K_csr:     per-bucket LDS counting sort by low byte -> rowstart/dinv/adj
// (R7 post-mortem: the old single-block scan_tot walked 196x391 ints
//  uncoalesced on one CU = 53us; now parallelized across the offsets pass.)
// Then gemm1 -> agg1(+bias,relu,residual) -> gemm2 -> agg2 -> d_out.

#define FDIM 128
#define GK 32
#define CHUNK 2048   // edges per chunk; nchunks = ceil(E/CHUNK) must be <= 512

__global__ void hist_kernel(const int* __restrict__ dst, int E, int nchunks, int nbk,
                            int* __restrict__ histT) {
    __shared__ int hist[256];
    int j = blockIdx.x, t = threadIdx.x;
    hist[t] = 0;
    __syncthreads();
    int base = j * CHUNK;
#pragma unroll
    for (int k = 0; k < CHUNK / 256; ++k) {
        int e = base + k * 256 + t;
        if (e < E) atomicAdd(&hist[dst[e] >> 8], 1);
    }
    __syncthreads();
    if (t < nbk) histT[t * nchunks + j] = hist[t];
}

// per-bucket: exclusive scan of chunk counts (LOCAL, no base), bucket total out
__global__ void offsets_kernel(int* __restrict__ histT, int nchunks,
                               int* __restrict__ tot) {
    __shared__ int s[512];
    int b = blockIdx.x, t = threadIdx.x;
    int* row = histT + (size_t)b * nchunks;
    int v = (t < nchunks) ? row[t] : 0;
    s[t] = v;
    __syncthreads();
    for (int off = 1; off < 512; off <<= 1) {
        int tv = (t >= off) ? s[t - off] : 0;
        __syncthreads();
        s[t] += tv;
        __syncthreads();
    }
    if (t < nchunks) row[t] = s[t] - v;     // local exclusive offset
    if (t == 511) tot[b] = s[511];          // bucket total
}

// 1 tiny block: exclusive scan of nbk totals -> base_, base_[nbk] = E
__global__ void base_kernel(const int* __restrict__ tot, int nbk, int* __restrict__ base_) {
    __shared__ int s[256];
    int t = threadIdx.x;
    int v = (t < nbk) ? tot[t] : 0;
    s[t] = v;
    __syncthreads();
    for (int off = 1; off < 256; off <<= 1) {
        int tv = (t >= off) ? s[t - off] : 0;
        __syncthreads();
        s[t] += tv;
        __syncthreads();
    }
    if (t < nbk) base_[t] = s[t] - v;
    if (t == 0) base_[nbk] = s[255];
}

__global__ void scatter_kernel(const int* __restrict__ ei, int E, int nchunks, int nbk,
                               const int* __restrict__ histT, const int* __restrict__ base_,
                               unsigned* __restrict__ bkt) {
    __shared__ int cur[256];
    int j = blockIdx.x, t = threadIdx.x;
    if (t < nbk) cur[t] = base_[t] + histT[t * nchunks + j];
    __syncthreads();
    int base = j * CHUNK;
#pragma unroll
    for (int k = 0; k < CHUNK / 256; ++k) {
        int e = base + k * 256 + t;
        if (e < E) {
            int src = ei[e];
            int d = ei[E + e];
            int pos = atomicAdd(&cur[d >> 8], 1);   // LDS atomic
            bkt[pos] = ((unsigned)(d & 255) << 24) | (unsigned)src;
        }
    }
}

__global__ void csr_kernel(const int* __restrict__ base_, const unsigned* __restrict__ bkt,
                           int* __restrict__ adj, int* __restrict__ rowstart,
                           float* __restrict__ dinv, int N, int nbk) {
    __shared__ int sbuf[256];
    __shared__ int hist[256];
    __shared__ int cur[256];
    int b = blockIdx.x, t = threadIdx.x;
    int bb = base_[b];
    int nb = base_[b + 1] - bb;
    hist[t] = 0;
    __syncthreads();
    const unsigned* bk = bkt + bb;
    for (int e = t; e < nb; e += 256) atomicAdd(&hist[bk[e] >> 24], 1);
    __syncthreads();
    int h_t = hist[t];
    sbuf[t] = h_t;
    __syncthreads();
    for (int off = 1; off < 256; off <<= 1) {
        int v = (t >= off) ? sbuf[t - off] : 0;
        __syncthreads();
        sbuf[t] += v;
        __syncthreads();
    }
    int excl_t = sbuf[t] - h_t;
    int node = b * 256 + t;
    if (node < N) {
        rowstart[node] = bb + excl_t;
        dinv[node] = rsqrtf((float)(h_t + 1));   // +1 self-loop
    }
    if (b == 0 && t == 0) rowstart[N] = base_[nbk];
    cur[t] = excl_t;
    __syncthreads();
    for (int e = t; e < nb; e += 256) {
        unsigned v = bk[e];
        int pos = atomicAdd(&cur[v >> 24], 1);   // LDS atomic
        adj[bb + pos] = (int)(v & 0xFFFFFFu);    // src < 2^24
    }
}

// ---- tiled GEMM1: h1 = x @ W1 (fp16 out), 128x128 block, 8x8/thread ----
__launch_bounds__(256, 2)
__global__ void gemm1_tiled(const float* __restrict__ x, const float* __restrict__ W,
                            __half* __restrict__ h, int N) {
    __shared__ float Ws[GK][128];
    __shared__ float xs[GK][132];
    int t = threadIdx.x;
    int tx = t & 15, ty = t >> 4;
    int i0 = blockIdx.x * 128;

    float acc[8][8];
#pragma unroll
    for (int a = 0; a < 8; ++a)
#pragma unroll
        for (int b = 0; b < 8; ++b) acc[a][b] = 0.f;

    for (int kb = 0; kb < FDIM / GK; ++kb) {
        __syncthreads();
        for (int p = t; p < 1024; p += 256) {
            float4 v = *(const float4*)(W + (size_t)(kb * GK + (p >> 5)) * 128 + ((p & 31) * 4));
            *(float4*)&Ws[p >> 5][(p & 31) * 4] = v;
        }
        int kq = (t & 7) * 4;
        int rb = t >> 3;
#pragma unroll
        for (int pass = 0; pass < 4; ++pass) {
            int r = pass * 32 + rb;
            int row = i0 + r;
            float4 v = make_float4(0.f, 0.f, 0.f, 0.f);
            if (row < N) v = *(const float4*)(x + (size_t)row * FDIM + kb * GK + kq);
            xs[kq + 0][r] = v.x;
            xs[kq + 1][r] = v.y;
            xs[kq + 2][r] = v.z;
            xs[kq + 3][r] = v.w;
        }
        __syncthreads();
#pragma unroll 4
        for (int k = 0; k < GK; ++k) {
            float4 a0 = *(const float4*)&xs[k][ty * 4];
            float4 a1 = *(const float4*)&xs[k][64 + ty * 4];
            float4 b0 = *(const float4*)&Ws[k][tx * 4];
            float4 b1 = *(const float4*)&Ws[k][64 + tx * 4];
            float av[8] = {a0.x, a0.y, a0.z, a0.w, a1.x, a1.y, a1.z, a1.w};
            float bv[8] = {b0.x, b0.y, b0.z, b0.w, b1.x, b1.y, b1.z, b1.w};
#pragma unroll
            for (int a = 0; a < 8; ++a)
#pragma unroll
                for (int b = 0; b < 8; ++b) acc[a][b] += av[a] * bv[b];
        }
    }
#pragma unroll
    for (int g = 0; g < 2; ++g)
#pragma unroll
        for (int a = 0; a < 4; ++a) {
            int row = i0 + g * 64 + ty * 4 + a;
            if (row < N) {
                int ri = g * 4 + a;
                union { __half2 hh[2]; float2 f; } u0, u1;
                u0.hh[0] = __floats2half2_rn(acc[ri][0], acc[ri][1]);
                u0.hh[1] = __floats2half2_rn(acc[ri][2], acc[ri][3]);
                u1.hh[0] = __floats2half2_rn(acc[ri][4], acc[ri][5]);
                u1.hh[1] = __floats2half2_rn(acc[ri][6], acc[ri][7]);
                *(float2*)(h + (size_t)row * FDIM + tx * 4) = u0.f;
                *(float2*)(h + (size_t)row * FDIM + 64 + tx * 4) = u1.f;
            }
        }
}

// z[i,:] = relu( dinv[i]*(sum_s h1[s,:]*dinv[s] + h1[i,:]*dinv[i]) + b1 ) + x[i,:]
__global__ void agg1_kernel(const __half* __restrict__ h1, const int* __restrict__ rowstart,
                            const int* __restrict__ adj, const float* __restrict__ dinv,
                            const float* __restrict__ x, const float* __restrict__ b1,
                            __half* __restrict__ z, int N) {
    int wave = threadIdx.x >> 6;
    int lane = threadIdx.x & 63;
    int i = blockIdx.x * 4 + wave;
    if (i >= N) return;
    int s0 = rowstart[i], s1 = rowstart[i + 1];
    float ax = 0.f, ay = 0.f;
    int n = s0;
    for (; n + 7 < s1; n += 8) {
        int s[8];
        float w[8];
        float2 r[8];
#pragma unroll
        for (int q = 0; q < 8; ++q) s[q] = adj[n + q];
#pragma unroll
        for (int q = 0; q < 8; ++q) w[q] = dinv[s[q]];
#pragma unroll
        for (int q = 0; q < 8; ++q)
            r[q] = __half22float2(((const __half2*)(h1 + (size_t)s[q] * FDIM))[lane]);
#pragma unroll
        for (int q = 0; q < 8; ++q) {
            ax += r[q].x * w[q];
            ay += r[q].y * w[q];
        }
    }
    for (; n < s1; ++n) {
        int sa = adj[n];
        float wa = dinv[sa];
        float2 ra = __half22float2(((const __half2*)(h1 + (size_t)sa * FDIM))[lane]);
        ax += ra.x * wa;
        ay += ra.y * wa;
    }
    float di = dinv[i];
    float self = di * di;
    float2 hi = __half22float2(((const __half2*)(h1 + (size_t)i * FDIM))[lane]);
    ax = ax * di + hi.x * self;
    ay = ay * di + hi.y * self;
    float2 bb = ((const float2*)b1)[lane];
    float2 xi = ((const float2*)(x + (size_t)i * FDIM))[lane];
    float rx = fmaxf(ax + bb.x, 0.f) + xi.x;
    float ry = fmaxf(ay + bb.y, 0.f) + xi.y;
    ((__half2*)(z + (size_t)i * FDIM))[lane] = __floats2half2_rn(rx, ry);
}

// ---- tiled GEMM2: h2 = z @ W2 (fp16 in, fp16 out, dense stride 40) ----
__launch_bounds__(256, 2)
__global__ void gemm2_tiled(const __half* __restrict__ z, const float* __restrict__ W2,
                            __half* __restrict__ h2, int N) {
    __shared__ float Ws[GK][64];
    __shared__ float zs[GK][132];
    int t = threadIdx.x;
    int tx = t & 15, ty = t >> 4;
    int i0 = blockIdx.x * 128;

    float acc[8][4];
#pragma unroll
    for (int a = 0; a < 8; ++a)
#pragma unroll
        for (int b = 0; b < 4; ++b) acc[a][b] = 0.f;

    for (int kb = 0; kb < FDIM / GK; ++kb) {
        __syncthreads();
        for (int p = t; p < GK * 64; p += 256) {
            int k = p >> 6, j = p & 63;
            Ws[k][j] = (j < 40) ? W2[(size_t)(kb * GK + k) * 40 + j] : 0.f;
        }
        int kq = (t & 3) * 8;
        int rb = t >> 2;
#pragma unroll
        for (int pass = 0; pass < 2; ++pass) {
            int r = pass * 64 + rb;
            int row = i0 + r;
            union { float4 v; __half2 hh[4]; } u;
            u.v = make_float4(0.f, 0.f, 0.f, 0.f);
            if (row < N) u.v = *(const float4*)(z + (size_t)row * FDIM + kb * GK + kq);
#pragma unroll
            for (int j = 0; j < 4; ++j) {
                float2 f = __half22float2(u.hh[j]);
                zs[kq + 2 * j][r] = f.x;
                zs[kq + 2 * j + 1][r] = f.y;
            }
        }
        __syncthreads();
#pragma unroll 4
        for (int k = 0; k < GK; ++k) {
            float4 a0 = *(const float4*)&zs[k][ty * 4];
            float4 a1 = *(const float4*)&zs[k][64 + ty * 4];
            float4 b0 = *(const float4*)&Ws[k][tx * 4];
            float av[8] = {a0.x, a0.y, a0.z, a0.w, a1.x, a1.y, a1.z, a1.w};
            float bv[4] = {b0.x, b0.y, b0.z, b0.w};
#pragma unroll
            for (int a = 0; a < 8; ++a)
#pragma unroll
                for (int b = 0; b < 4; ++b) acc[a][b] += av[a] * bv[b];
        }
    }
    if (tx < 10) {
#pragma unroll
        for (int g = 0; g < 2; ++g)
#pragma unroll
            for (int a = 0; a < 4; ++a) {
                int row = i0 + g * 64 + ty * 4 + a;
                if (row < N) {
                    int ri = g * 4 + a;
                    union { __half2 hh[2]; float2 f; } u;
                    u.hh[0] = __floats2half2_rn(acc[ri][0], acc[ri][1]);
                    u.hh[1] = __floats2half2_rn(acc[ri][2], acc[ri][3]);
                    *(float2*)(h2 + (size_t)row * 40 + tx * 4) = u.f;
                }
            }
    }
}

// y[i,:] = dinv[i]*(sum_s h2[s,:]*dinv[s] + h2[i,:]*dinv[i]) + b2
__global__ void agg2_kernel(const __half* __restrict__ h2, const int* __restrict__ rowstart,
                            const int* __restrict__ adj, const float* __restrict__ dinv,
                            const float* __restrict__ b2, float* __restrict__ y, int N) {
    int wave = threadIdx.x >> 6;
    int lane = threadIdx.x & 63;
    int i = blockIdx.x * 4 + wave;
    if (i >= N) return;
    int e = (lane >= 40) ? 2 : ((lane >= 20) ? 1 : 0);
    int f = lane - 20 * e;
    int s0 = rowstart[i], s1 = rowstart[i + 1];
    float ax = 0.f, ay = 0.f;
    if (lane < 60) {
        int n = s0 + e;
        for (; n + 9 < s1; n += 12) {
            int s[4];
            float w[4];
            float2 r[4];
#pragma unroll
            for (int q = 0; q < 4; ++q) s[q] = adj[n + 3 * q];
#pragma unroll
            for (int q = 0; q < 4; ++q) w[q] = dinv[s[q]];
#pragma unroll
            for (int q = 0; q < 4; ++q)
                r[q] = __half22float2(((const __half2*)(h2 + (size_t)s[q] * 40))[f]);
#pragma unroll
            for (int q = 0; q < 4; ++q) {
                ax += r[q].x * w[q];
                ay += r[q].y * w[q];
            }
        }
        for (; n < s1; n += 3) {
            int sa = adj[n];
            float wa = dinv[sa];
            float2 ra = __half22float2(((const __half2*)(h2 + (size_t)sa * 40))[f]);
            ax += ra.x * wa;
            ay += ra.y * wa;
        }
    }
    float sx = ax + __shfl(ax, lane + 20, 64) + __shfl(ax, lane + 40, 64);
    float sy = ay + __shfl(ay, lane + 20, 64) + __shfl(ay, lane + 40, 64);
    if (lane < 20) {
        float di = dinv[i];
        float2 hi = __half22float2(((const __half2*)(h2 + (size_t)i * 40))[lane]);
        float2 bb = ((const float2*)b2)[lane];
        float2 res;
        res.x = sx * di + hi.x * di * di + bb.x;
        res.y = sy * di + hi.y * di * di + bb.y;
        ((float2*)(y + (size_t)i * 40))[lane] = res;
    }
}

extern "C" void kernel_launch(void* const* d_in, const int* in_sizes, int n_in,
                              void* d_out, int out_size, void* d_ws, size_t ws_size,
                              hipStream_t stream) {
    const float* x  = (const float*)d_in[0];
    const int*   ei = (const int*)d_in[1];
    const float* W1 = (const float*)d_in[2];
    const float* b1 = (const float*)d_in[3];
    const float* W2 = (const float*)d_in[4];
    const float* b2 = (const float*)d_in[5];
    float* y = (float*)d_out;

    const int H = in_sizes[3];           // 128
    const int F = in_sizes[2] / H;       // 128
    const int N = in_sizes[0] / F;       // 50000
    const int E = in_sizes[1] / 2;       // 800000
    (void)H; (void)ws_size; (void)n_in; (void)out_size;

    const int nbk = (N + 255) >> 8;              // 196 buckets (<=256)
    const int nchunks = (E + CHUNK - 1) / CHUNK; // 391 (<=512)

    size_t off = 0;
    auto carve = [&](size_t bytes) -> void* {
        void* p = (char*)d_ws + off;
        off += (bytes + 255) & ~(size_t)255;
        return p;
    };
    int*      histT    = (int*)carve((size_t)nbk * nchunks * 4);
    int*      tot      = (int*)carve((size_t)nbk * 4);
    int*      base_    = (int*)carve((size_t)(nbk + 1) * 4);
    unsigned* bkt      = (unsigned*)carve((size_t)E * 4);
    int*      rowstart = (int*)carve((size_t)(N + 1) * 4);
    float*    dinv     = (float*)carve((size_t)N * 4);
    int*      adj      = (int*)carve((size_t)E * 4);
    __half*   h1       = (__half*)carve((size_t)N * FDIM * 2);
    __half*   z        = (__half*)carve((size_t)N * FDIM * 2);
    __half*   h2       = h1;   // h1 dead after agg1; h2 = N x 40 fp16 (fits)

    hist_kernel<<<nchunks, 256, 0, stream>>>(ei + E, E, nchunks, nbk, histT);
    offsets_kernel<<<nbk, 512, 0, stream>>>(histT, nchunks, tot);
    base_kernel<<<1, 256, 0, stream>>>(tot, nbk, base_);
    scatter_kernel<<<nchunks, 256, 0, stream>>>(ei, E, nchunks, nbk, histT, base_, bkt);
    csr_kernel<<<nbk, 256, 0, stream>>>(base_, bkt, adj, rowstart, dinv, N, nbk);

    int nbt = (N + 127) / 128;
    gemm1_tiled<<<nbt, 256, 0, stream>>>(x, W1, h1, N);
    agg1_kernel<<<(N + 3) / 4, 256, 0, stream>>>(h1, rowstart, adj, dinv, x, b1, z, N);
    gemm2_tiled<<<nbt, 256, 0, stream>>>(z, W2, h2, N);
    agg2_kernel<<<(N + 3) / 4, 256, 0, stream>>>(h2, rowstart, adj, dinv, b2, y, N);
}

// Round 9
// 202.522 us; speedup vs baseline: 1.4639x; 1.1478x over previous
//
#include <hip/hip_runtime.h>
#include <hip/hip_fp16.h>

// 2-layer GCN, pull-based CSR aggregation. fp32 math, fp16 intermediates.
// CSR build with ZERO global atomics:
//   K_hist:    per-2048-edge-chunk LDS histogram of dst>>8 -> histT[bkt][chunk]
//   K_offsets: per-bucket exclusive scan over chunks (bucket-LOCAL) + tot[b]
//   K_scatter: in-LDS scan of tot -> base; cursors = base + local offset
//   K_csr:     same in-LDS scan; per-bucket counting sort -> rowstart/dinv/adj
// gemm1 is MFMA f16 (16x16x32, fp32 accum): x cast to fp16 during staging.
// Then agg1(+bias,relu,residual) -> gemm2(vector) -> agg2 -> d_out.

#define FDIM 128
#define GK 32
#define CHUNK 2048   // edges per chunk; nchunks = ceil(E/CHUNK) must be <= 512

using half8  = __attribute__((ext_vector_type(8))) _Float16;
using float4v = __attribute__((ext_vector_type(4))) float;

__global__ void hist_kernel(const int* __restrict__ dst, int E, int nchunks, int nbk,
                            int* __restrict__ histT) {
    __shared__ int hist[256];
    int j = blockIdx.x, t = threadIdx.x;
    hist[t] = 0;
    __syncthreads();
    int base = j * CHUNK;
#pragma unroll
    for (int k = 0; k < CHUNK / 256; ++k) {
        int e = base + k * 256 + t;
        if (e < E) atomicAdd(&hist[dst[e] >> 8], 1);
    }
    __syncthreads();
    if (t < nbk) histT[t * nchunks + j] = hist[t];
}

// per-bucket: exclusive scan of chunk counts (LOCAL, no base), bucket total out
__global__ void offsets_kernel(int* __restrict__ histT, int nchunks,
                               int* __restrict__ tot) {
    __shared__ int s[512];
    int b = blockIdx.x, t = threadIdx.x;
    int* row = histT + (size_t)b * nchunks;
    int v = (t < nchunks) ? row[t] : 0;
    s[t] = v;
    __syncthreads();
    for (int off = 1; off < 512; off <<= 1) {
        int tv = (t >= off) ? s[t - off] : 0;
        __syncthreads();
        s[t] += tv;
        __syncthreads();
    }
    if (t < nchunks) row[t] = s[t] - v;     // local exclusive offset
    if (t == 511) tot[b] = s[511];          // bucket total
}

__global__ void scatter_kernel(const int* __restrict__ ei, int E, int nchunks, int nbk,
                               const int* __restrict__ histT, const int* __restrict__ tot,
                               unsigned* __restrict__ bkt) {
    __shared__ int s[256];
    __shared__ int cur[256];
    int j = blockIdx.x, t = threadIdx.x;
    // in-LDS exclusive scan of bucket totals -> base
    int v = (t < nbk) ? tot[t] : 0;
    s[t] = v;
    __syncthreads();
    for (int off = 1; off < 256; off <<= 1) {
        int tv = (t >= off) ? s[t - off] : 0;
        __syncthreads();
        s[t] += tv;
        __syncthreads();
    }
    if (t < nbk) cur[t] = (s[t] - v) + histT[t * nchunks + j];
    __syncthreads();
    int base = j * CHUNK;
#pragma unroll
    for (int k = 0; k < CHUNK / 256; ++k) {
        int e = base + k * 256 + t;
        if (e < E) {
            int src = ei[e];
            int d = ei[E + e];
            int pos = atomicAdd(&cur[d >> 8], 1);   // LDS atomic
            bkt[pos] = ((unsigned)(d & 255) << 24) | (unsigned)src;
        }
    }
}

__global__ void csr_kernel(const int* __restrict__ tot, const unsigned* __restrict__ bkt,
                           int* __restrict__ adj, int* __restrict__ rowstart,
                           float* __restrict__ dinv, int N, int nbk, int E) {
    __shared__ int sbuf[256];
    __shared__ int hist[256];
    __shared__ int cur[256];
    int b = blockIdx.x, t = threadIdx.x;
    // in-LDS exclusive scan of bucket totals -> this bucket's base
    int v = (t < nbk) ? tot[t] : 0;
    sbuf[t] = v;
    __syncthreads();
    for (int off = 1; off < 256; off <<= 1) {
        int tv = (t >= off) ? sbuf[t - off] : 0;
        __syncthreads();
        sbuf[t] += tv;
        __syncthreads();
    }
    int bb = sbuf[b] - ((b < nbk) ? tot[b] : 0);   // exclusive base of bucket b
    int nb = tot[b];
    __syncthreads();
    hist[t] = 0;
    __syncthreads();
    const unsigned* bk = bkt + bb;
    for (int e = t; e < nb; e += 256) atomicAdd(&hist[bk[e] >> 24], 1);
    __syncthreads();
    int h_t = hist[t];
    sbuf[t] = h_t;
    __syncthreads();
    for (int off = 1; off < 256; off <<= 1) {
        int vv = (t >= off) ? sbuf[t - off] : 0;
        __syncthreads();
        sbuf[t] += vv;
        __syncthreads();
    }
    int excl_t = sbuf[t] - h_t;
    int node = b * 256 + t;
    if (node < N) {
        rowstart[node] = bb + excl_t;
        dinv[node] = rsqrtf((float)(h_t + 1));   // +1 self-loop
    }
    if (b == 0 && t == 0) rowstart[N] = E;
    cur[t] = excl_t;
    __syncthreads();
    for (int e = t; e < nb; e += 256) {
        unsigned vv = bk[e];
        int pos = atomicAdd(&cur[vv >> 24], 1);   // LDS atomic
        adj[bb + pos] = (int)(vv & 0xFFFFFFu);    // src < 2^24
    }
}

// ---- MFMA GEMM1: h1 = fp16(x) @ fp16(W1), fp32 accum, fp16 out ----
// 128-row tile per block, K=128 in one shot. LDS: Xs[128][136] + Wt[128][136]
// (Wt transposed, +8-half pad -> <=2-way b128 conflicts). 4 waves x 32 rows.
__launch_bounds__(256, 2)
__global__ void gemm1_mfma(const float* __restrict__ x, const float* __restrict__ W,
                           _Float16* __restrict__ h, int N) {
    __shared__ _Float16 Xs[128 * 136];
    __shared__ _Float16 Wt[128 * 136];
    int t = threadIdx.x;
    int i0 = blockIdx.x * 128;

    // stage X tile (fp32 -> fp16), coalesced float4 reads
    for (int p = t; p < 128 * 32; p += 256) {
        int row = p >> 5;            // 0..127
        int col4 = (p & 31) * 4;     // 0..124
        int grow = i0 + row;
        float4 v = make_float4(0.f, 0.f, 0.f, 0.f);
        if (grow < N) v = *(const float4*)(x + (size_t)grow * FDIM + col4);
        _Float16* d = &Xs[row * 136 + col4];
        d[0] = (_Float16)v.x;
        d[1] = (_Float16)v.y;
        d[2] = (_Float16)v.z;
        d[3] = (_Float16)v.w;
    }
    // stage W transposed (fp32 -> fp16): Wt[n][k] = W[k][n]
    for (int p = t; p < 128 * 128; p += 256) {
        int k = p >> 7;
        int n = p & 127;
        Wt[n * 136 + k] = (_Float16)W[k * 128 + n];
    }
    __syncthreads();

    int lane = t & 63, w = t >> 6;
    int c = lane & 15, q = lane >> 4;
    int m0 = w * 32;

    float4v acc[2][8];
#pragma unroll
    for (int r = 0; r < 2; ++r)
#pragma unroll
        for (int nt = 0; nt < 8; ++nt) acc[r][nt] = (float4v)(0.f);

#pragma unroll
    for (int kk = 0; kk < 4; ++kk) {
        int k0 = kk * 32 + q * 8;
        half8 a0 = *(const half8*)&Xs[(m0 + c) * 136 + k0];
        half8 a1 = *(const half8*)&Xs[(m0 + 16 + c) * 136 + k0];
#pragma unroll
        for (int nt = 0; nt < 8; ++nt) {
            half8 bv = *(const half8*)&Wt[(nt * 16 + c) * 136 + k0];
            acc[0][nt] = __builtin_amdgcn_mfma_f32_16x16x32_f16(a0, bv, acc[0][nt], 0, 0, 0);
            acc[1][nt] = __builtin_amdgcn_mfma_f32_16x16x32_f16(a1, bv, acc[1][nt], 0, 0, 0);
        }
    }
    // epilogue: C layout col=lane&15, row=(lane>>4)*4+reg
#pragma unroll
    for (int r = 0; r < 2; ++r)
#pragma unroll
        for (int reg = 0; reg < 4; ++reg) {
            int row = i0 + m0 + r * 16 + q * 4 + reg;
            if (row < N) {
#pragma unroll
                for (int nt = 0; nt < 8; ++nt)
                    h[(size_t)row * FDIM + nt * 16 + c] = (_Float16)acc[r][nt][reg];
            }
        }
}

// z[i,:] = relu( dinv[i]*(sum_s h1[s,:]*dinv[s] + h1[i,:]*dinv[i]) + b1 ) + x[i,:]
__global__ void agg1_kernel(const __half* __restrict__ h1, const int* __restrict__ rowstart,
                            const int* __restrict__ adj, const float* __restrict__ dinv,
                            const float* __restrict__ x, const float* __restrict__ b1,
                            __half* __restrict__ z, int N) {
    int wave = threadIdx.x >> 6;
    int lane = threadIdx.x & 63;
    int i = blockIdx.x * 4 + wave;
    if (i >= N) return;
    int s0 = rowstart[i], s1 = rowstart[i + 1];
    float ax = 0.f, ay = 0.f;
    int n = s0;
    for (; n + 7 < s1; n += 8) {
        int s[8];
        float w[8];
        float2 r[8];
#pragma unroll
        for (int q = 0; q < 8; ++q) s[q] = adj[n + q];
#pragma unroll
        for (int q = 0; q < 8; ++q) w[q] = dinv[s[q]];
#pragma unroll
        for (int q = 0; q < 8; ++q)
            r[q] = __half22float2(((const __half2*)(h1 + (size_t)s[q] * FDIM))[lane]);
#pragma unroll
        for (int q = 0; q < 8; ++q) {
            ax += r[q].x * w[q];
            ay += r[q].y * w[q];
        }
    }
    if (n + 3 < s1) {
        int s[4];
        float w[4];
        float2 r[4];
#pragma unroll
        for (int q = 0; q < 4; ++q) s[q] = adj[n + q];
#pragma unroll
        for (int q = 0; q < 4; ++q) w[q] = dinv[s[q]];
#pragma unroll
        for (int q = 0; q < 4; ++q)
            r[q] = __half22float2(((const __half2*)(h1 + (size_t)s[q] * FDIM))[lane]);
#pragma unroll
        for (int q = 0; q < 4; ++q) {
            ax += r[q].x * w[q];
            ay += r[q].y * w[q];
        }
        n += 4;
    }
    for (; n < s1; ++n) {
        int sa = adj[n];
        float wa = dinv[sa];
        float2 ra = __half22float2(((const __half2*)(h1 + (size_t)sa * FDIM))[lane]);
        ax += ra.x * wa;
        ay += ra.y * wa;
    }
    float di = dinv[i];
    float self = di * di;
    float2 hi = __half22float2(((const __half2*)(h1 + (size_t)i * FDIM))[lane]);
    ax = ax * di + hi.x * self;
    ay = ay * di + hi.y * self;
    float2 bb = ((const float2*)b1)[lane];
    float2 xi = ((const float2*)(x + (size_t)i * FDIM))[lane];
    float rx = fmaxf(ax + bb.x, 0.f) + xi.x;
    float ry = fmaxf(ay + bb.y, 0.f) + xi.y;
    ((__half2*)(z + (size_t)i * FDIM))[lane] = __floats2half2_rn(rx, ry);
}

// ---- tiled GEMM2: h2 = z @ W2 (fp16 in, fp16 out, dense stride 40) ----
__launch_bounds__(256, 2)
__global__ void gemm2_tiled(const __half* __restrict__ z, const float* __restrict__ W2,
                            __half* __restrict__ h2, int N) {
    __shared__ float Ws[GK][64];
    __shared__ float zs[GK][132];
    int t = threadIdx.x;
    int tx = t & 15, ty = t >> 4;
    int i0 = blockIdx.x * 128;

    float acc[8][4];
#pragma unroll
    for (int a = 0; a < 8; ++a)
#pragma unroll
        for (int b = 0; b < 4; ++b) acc[a][b] = 0.f;

    for (int kb = 0; kb < FDIM / GK; ++kb) {
        __syncthreads();
        for (int p = t; p < GK * 64; p += 256) {
            int k = p >> 6, j = p & 63;
            Ws[k][j] = (j < 40) ? W2[(size_t)(kb * GK + k) * 40 + j] : 0.f;
        }
        int kq = (t & 3) * 8;
        int rb = t >> 2;
#pragma unroll
        for (int pass = 0; pass < 2; ++pass) {
            int r = pass * 64 + rb;
            int row = i0 + r;
            union { float4 v; __half2 hh[4]; } u;
            u.v = make_float4(0.f, 0.f, 0.f, 0.f);
            if (row < N) u.v = *(const float4*)(z + (size_t)row * FDIM + kb * GK + kq);
#pragma unroll
            for (int j = 0; j < 4; ++j) {
                float2 f = __half22float2(u.hh[j]);
                zs[kq + 2 * j][r] = f.x;
                zs[kq + 2 * j + 1][r] = f.y;
            }
        }
        __syncthreads();
#pragma unroll 4
        for (int k = 0; k < GK; ++k) {
            float4 a0 = *(const float4*)&zs[k][ty * 4];
            float4 a1 = *(const float4*)&zs[k][64 + ty * 4];
            float4 b0 = *(const float4*)&Ws[k][tx * 4];
            float av[8] = {a0.x, a0.y, a0.z, a0.w, a1.x, a1.y, a1.z, a1.w};
            float bv[4] = {b0.x, b0.y, b0.z, b0.w};
#pragma unroll
            for (int a = 0; a < 8; ++a)
#pragma unroll
                for (int b = 0; b < 4; ++b) acc[a][b] += av[a] * bv[b];
        }
    }
    if (tx < 10) {
#pragma unroll
        for (int g = 0; g < 2; ++g)
#pragma unroll
            for (int a = 0; a < 4; ++a) {
                int row = i0 + g * 64 + ty * 4 + a;
                if (row < N) {
                    int ri = g * 4 + a;
                    union { __half2 hh[2]; float2 f; } u;
                    u.hh[0] = __floats2half2_rn(acc[ri][0], acc[ri][1]);
                    u.hh[1] = __floats2half2_rn(acc[ri][2], acc[ri][3]);
                    *(float2*)(h2 + (size_t)row * 40 + tx * 4) = u.f;
                }
            }
    }
}

// y[i,:] = dinv[i]*(sum_s h2[s,:]*dinv[s] + h2[i,:]*dinv[i]) + b2
__global__ void agg2_kernel(const __half* __restrict__ h2, const int* __restrict__ rowstart,
                            const int* __restrict__ adj, const float* __restrict__ dinv,
                            const float* __restrict__ b2, float* __restrict__ y, int N) {
    int wave = threadIdx.x >> 6;
    int lane = threadIdx.x & 63;
    int i = blockIdx.x * 4 + wave;
    if (i >= N) return;
    int e = (lane >= 40) ? 2 : ((lane >= 20) ? 1 : 0);
    int f = lane - 20 * e;
    int s0 = rowstart[i], s1 = rowstart[i + 1];
    float ax = 0.f, ay = 0.f;
    if (lane < 60) {
        int n = s0 + e;
        for (; n + 9 < s1; n += 12) {
            int s[4];
            float w[4];
            float2 r[4];
#pragma unroll
            for (int q = 0; q < 4; ++q) s[q] = adj[n + 3 * q];
#pragma unroll
            for (int q = 0; q < 4; ++q) w[q] = dinv[s[q]];
#pragma unroll
            for (int q = 0; q < 4; ++q)
                r[q] = __half22float2(((const __half2*)(h2 + (size_t)s[q] * 40))[f]);
#pragma unroll
            for (int q = 0; q < 4; ++q) {
                ax += r[q].x * w[q];
                ay += r[q].y * w[q];
            }
        }
        for (; n < s1; n += 3) {
            int sa = adj[n];
            float wa = dinv[sa];
            float2 ra = __half22float2(((const __half2*)(h2 + (size_t)sa * 40))[f]);
            ax += ra.x * wa;
            ay += ra.y * wa;
        }
    }
    float sx = ax + __shfl(ax, lane + 20, 64) + __shfl(ax, lane + 40, 64);
    float sy = ay + __shfl(ay, lane + 20, 64) + __shfl(ay, lane + 40, 64);
    if (lane < 20) {
        float di = dinv[i];
        float2 hi = __half22float2(((const __half2*)(h2 + (size_t)i * 40))[lane]);
        float2 bb = ((const float2*)b2)[lane];
        float2 res;
        res.x = sx * di + hi.x * di * di + bb.x;
        res.y = sy * di + hi.y * di * di + bb.y;
        ((float2*)(y + (size_t)i * 40))[lane] = res;
    }
}

extern "C" void kernel_launch(void* const* d_in, const int* in_sizes, int n_in,
                              void* d_out, int out_size, void* d_ws, size_t ws_size,
                              hipStream_t stream) {
    const float* x  = (const float*)d_in[0];
    const int*   ei = (const int*)d_in[1];
    const float* W1 = (const float*)d_in[2];
    const float* b1 = (const float*)d_in[3];
    const float* W2 = (const float*)d_in[4];
    const float* b2 = (const float*)d_in[5];
    float* y = (float*)d_out;

    const int H = in_sizes[3];           // 128
    const int F = in_sizes[2] / H;       // 128
    const int N = in_sizes[0] / F;       // 50000
    const int E = in_sizes[1] / 2;       // 800000
    (void)H; (void)ws_size; (void)n_in; (void)out_size;

    const int nbk = (N + 255) >> 8;              // 196 buckets (<=256)
    const int nchunks = (E + CHUNK - 1) / CHUNK; // 391 (<=512)

    size_t off = 0;
    auto carve = [&](size_t bytes) -> void* {
        void* p = (char*)d_ws + off;
        off += (bytes + 255) & ~(size_t)255;
        return p;
    };
    int*      histT    = (int*)carve((size_t)nbk * nchunks * 4);
    int*      tot      = (int*)carve((size_t)nbk * 4);
    unsigned* bkt      = (unsigned*)carve((size_t)E * 4);
    int*      rowstart = (int*)carve((size_t)(N + 1) * 4);
    float*    dinv     = (float*)carve((size_t)N * 4);
    int*      adj      = (int*)carve((size_t)E * 4);
    __half*   h1       = (__half*)carve((size_t)N * FDIM * 2);
    __half*   z        = (__half*)carve((size_t)N * FDIM * 2);
    __half*   h2       = h1;   // h1 dead after agg1; h2 = N x 40 fp16 (fits)

    hist_kernel<<<nchunks, 256, 0, stream>>>(ei + E, E, nchunks, nbk, histT);
    offsets_kernel<<<nbk, 512, 0, stream>>>(histT, nchunks, tot);
    scatter_kernel<<<nchunks, 256, 0, stream>>>(ei, E, nchunks, nbk, histT, tot, bkt);
    csr_kernel<<<nbk, 256, 0, stream>>>(tot, bkt, adj, rowstart, dinv, N, nbk, E);

    int nbt = (N + 127) / 128;
    gemm1_mfma<<<nbt, 256, 0, stream>>>(x, W1, (_Float16*)h1, N);
    agg1_kernel<<<(N + 3) / 4, 256, 0, stream>>>(h1, rowstart, adj, dinv, x, b1, z, N);
    gemm2_tiled<<<nbt, 256, 0, stream>>>(z, W2, h2, N);
    agg2_kernel<<<(N + 3) / 4, 256, 0, stream>>>(h2, rowstart, adj, dinv, b2, y, N);
}

// Round 10
// 202.448 us; speedup vs baseline: 1.4644x; 1.0004x over previous
//
#include <hip/hip_runtime.h>
#include <hip/hip_fp16.h>

// 2-layer GCN, pull-based CSR aggregation. fp32 math; h1 stored fp8-e4m3
// (HW cvt, halves the dominant agg1 gather traffic), z/h2 fp16.
// CSR build with ZERO global atomics (R5/R6: device atomics cap ~6/cyc):
//   K_hist -> K_offsets -> K_scatter -> K_csr  (LDS atomics + scans only)
// gemm1 is MFMA f16 (16x16x32, fp32 accum) with fp8 epilogue via LDS.
// Then agg1(+bias,relu,residual) -> gemm2(vector) -> agg2 -> d_out.

#define FDIM 128
#define GK 32
#define CHUNK 2048   // edges per chunk; nchunks = ceil(E/CHUNK) must be <= 512

using half8   = __attribute__((ext_vector_type(8))) _Float16;
using float4v = __attribute__((ext_vector_type(4))) float;
using float2v = __attribute__((ext_vector_type(2))) float;

__device__ __forceinline__ float2v fp8x2_to_f32x2(unsigned short hv) {
    return __builtin_amdgcn_cvt_pk_f32_fp8((int)hv, false);
}
__device__ __forceinline__ unsigned char f32_to_fp8(float v) {
    return (unsigned char)(__builtin_amdgcn_cvt_pk_fp8_f32(v, v, 0, false) & 0xFF);
}

__global__ void hist_kernel(const int* __restrict__ dst, int E, int nchunks, int nbk,
                            int* __restrict__ histT) {
    __shared__ int hist[256];
    int j = blockIdx.x, t = threadIdx.x;
    hist[t] = 0;
    __syncthreads();
    int base = j * CHUNK;
#pragma unroll
    for (int k = 0; k < CHUNK / 256; ++k) {
        int e = base + k * 256 + t;
        if (e < E) atomicAdd(&hist[dst[e] >> 8], 1);
    }
    __syncthreads();
    if (t < nbk) histT[t * nchunks + j] = hist[t];
}

// per-bucket: exclusive scan of chunk counts (LOCAL, no base), bucket total out
__global__ void offsets_kernel(int* __restrict__ histT, int nchunks,
                               int* __restrict__ tot) {
    __shared__ int s[512];
    int b = blockIdx.x, t = threadIdx.x;
    int* row = histT + (size_t)b * nchunks;
    int v = (t < nchunks) ? row[t] : 0;
    s[t] = v;
    __syncthreads();
    for (int off = 1; off < 512; off <<= 1) {
        int tv = (t >= off) ? s[t - off] : 0;
        __syncthreads();
        s[t] += tv;
        __syncthreads();
    }
    if (t < nchunks) row[t] = s[t] - v;     // local exclusive offset
    if (t == 511) tot[b] = s[511];          // bucket total
}

__global__ void scatter_kernel(const int* __restrict__ ei, int E, int nchunks, int nbk,
                               const int* __restrict__ histT, const int* __restrict__ tot,
                               unsigned* __restrict__ bkt) {
    __shared__ int s[256];
    __shared__ int cur[256];
    int j = blockIdx.x, t = threadIdx.x;
    int v = (t < nbk) ? tot[t] : 0;
    s[t] = v;
    __syncthreads();
    for (int off = 1; off < 256; off <<= 1) {
        int tv = (t >= off) ? s[t - off] : 0;
        __syncthreads();
        s[t] += tv;
        __syncthreads();
    }
    if (t < nbk) cur[t] = (s[t] - v) + histT[t * nchunks + j];
    __syncthreads();
    int base = j * CHUNK;
#pragma unroll
    for (int k = 0; k < CHUNK / 256; ++k) {
        int e = base + k * 256 + t;
        if (e < E) {
            int src = ei[e];
            int d = ei[E + e];
            int pos = atomicAdd(&cur[d >> 8], 1);   // LDS atomic
            bkt[pos] = ((unsigned)(d & 255) << 24) | (unsigned)src;
        }
    }
}

__global__ void csr_kernel(const int* __restrict__ tot, const unsigned* __restrict__ bkt,
                           int* __restrict__ adj, int* __restrict__ rowstart,
                           float* __restrict__ dinv, int N, int nbk, int E) {
    __shared__ int sbuf[256];
    __shared__ int hist[256];
    __shared__ int cur[256];
    int b = blockIdx.x, t = threadIdx.x;
    int v = (t < nbk) ? tot[t] : 0;
    sbuf[t] = v;
    __syncthreads();
    for (int off = 1; off < 256; off <<= 1) {
        int tv = (t >= off) ? sbuf[t - off] : 0;
        __syncthreads();
        sbuf[t] += tv;
        __syncthreads();
    }
    int bb = sbuf[b] - ((b < nbk) ? tot[b] : 0);
    int nb = tot[b];
    __syncthreads();
    hist[t] = 0;
    __syncthreads();
    const unsigned* bk = bkt + bb;
    for (int e = t; e < nb; e += 256) atomicAdd(&hist[bk[e] >> 24], 1);
    __syncthreads();
    int h_t = hist[t];
    sbuf[t] = h_t;
    __syncthreads();
    for (int off = 1; off < 256; off <<= 1) {
        int vv = (t >= off) ? sbuf[t - off] : 0;
        __syncthreads();
        sbuf[t] += vv;
        __syncthreads();
    }
    int excl_t = sbuf[t] - h_t;
    int node = b * 256 + t;
    if (node < N) {
        rowstart[node] = bb + excl_t;
        dinv[node] = rsqrtf((float)(h_t + 1));   // +1 self-loop
    }
    if (b == 0 && t == 0) rowstart[N] = E;
    cur[t] = excl_t;
    __syncthreads();
    for (int e = t; e < nb; e += 256) {
        unsigned vv = bk[e];
        int pos = atomicAdd(&cur[vv >> 24], 1);   // LDS atomic
        adj[bb + pos] = (int)(vv & 0xFFFFFFu);    // src < 2^24
    }
}

// ---- MFMA GEMM1: h1 = fp16(x) @ fp16(W1), fp32 accum, fp8-e4m3 out ----
// 128-row tile per block, K=128 one shot. LDS Xs[128][136]+Wt[128][136].
// Epilogue: encode fp8 into LDS tile (reuse Xs), then coalesced 4B stores.
__launch_bounds__(256, 2)
__global__ void gemm1_mfma(const float* __restrict__ x, const float* __restrict__ W,
                           unsigned char* __restrict__ h, int N) {
    __shared__ _Float16 Xs[128 * 136];
    __shared__ _Float16 Wt[128 * 136];
    int t = threadIdx.x;
    int i0 = blockIdx.x * 128;

    for (int p = t; p < 128 * 32; p += 256) {
        int row = p >> 5;
        int col4 = (p & 31) * 4;
        int grow = i0 + row;
        float4 v = make_float4(0.f, 0.f, 0.f, 0.f);
        if (grow < N) v = *(const float4*)(x + (size_t)grow * FDIM + col4);
        _Float16* d = &Xs[row * 136 + col4];
        d[0] = (_Float16)v.x;
        d[1] = (_Float16)v.y;
        d[2] = (_Float16)v.z;
        d[3] = (_Float16)v.w;
    }
    for (int p = t; p < 128 * 128; p += 256) {
        int k = p >> 7;
        int n = p & 127;
        Wt[n * 136 + k] = (_Float16)W[k * 128 + n];
    }
    __syncthreads();

    int lane = t & 63, w = t >> 6;
    int c = lane & 15, q = lane >> 4;
    int m0 = w * 32;

    float4v acc[2][8];
#pragma unroll
    for (int r = 0; r < 2; ++r)
#pragma unroll
        for (int nt = 0; nt < 8; ++nt) acc[r][nt] = (float4v)(0.f);

#pragma unroll
    for (int kk = 0; kk < 4; ++kk) {
        int k0 = kk * 32 + q * 8;
        half8 a0 = *(const half8*)&Xs[(m0 + c) * 136 + k0];
        half8 a1 = *(const half8*)&Xs[(m0 + 16 + c) * 136 + k0];
#pragma unroll
        for (int nt = 0; nt < 8; ++nt) {
            half8 bv = *(const half8*)&Wt[(nt * 16 + c) * 136 + k0];
            acc[0][nt] = __builtin_amdgcn_mfma_f32_16x16x32_f16(a0, bv, acc[0][nt], 0, 0, 0);
            acc[1][nt] = __builtin_amdgcn_mfma_f32_16x16x32_f16(a1, bv, acc[1][nt], 0, 0, 0);
        }
    }
    __syncthreads();   // Xs/Wt dead; reuse Xs as fp8 tile T[128][128]
    unsigned char* T = (unsigned char*)Xs;
#pragma unroll
    for (int r = 0; r < 2; ++r)
#pragma unroll
        for (int reg = 0; reg < 4; ++reg) {
            int rl = m0 + r * 16 + q * 4 + reg;
#pragma unroll
            for (int nt = 0; nt < 8; ++nt)
                T[rl * 128 + nt * 16 + c] = f32_to_fp8(acc[r][nt][reg]);
        }
    __syncthreads();
    for (int p = t; p < 128 * 32; p += 256) {
        int row = p >> 5;
        int col4 = (p & 31) * 4;
        int grow = i0 + row;
        if (grow < N)
            *(unsigned*)(h + (size_t)grow * 128 + col4) = *(const unsigned*)&T[row * 128 + col4];
    }
}

// z[i,:] = relu( dinv[i]*(sum_s h1[s,:]*dinv[s] + h1[i,:]*dinv[i]) + b1 ) + x[i,:]
// h1 is fp8-e4m3, 128 B/row; lane = 2 feats; 8 gathers in flight.
__global__ void agg1_kernel(const unsigned char* __restrict__ h1, const int* __restrict__ rowstart,
                            const int* __restrict__ adj, const float* __restrict__ dinv,
                            const float* __restrict__ x, const float* __restrict__ b1,
                            __half* __restrict__ z, int N) {
    int wave = threadIdx.x >> 6;
    int lane = threadIdx.x & 63;
    int i = blockIdx.x * 4 + wave;
    if (i >= N) return;
    int s0 = rowstart[i], s1 = rowstart[i + 1];
    float ax = 0.f, ay = 0.f;
    int n = s0;
    for (; n + 7 < s1; n += 8) {
        int s[8];
        float w[8];
        unsigned short hv[8];
#pragma unroll
        for (int q = 0; q < 8; ++q) s[q] = adj[n + q];
#pragma unroll
        for (int q = 0; q < 8; ++q) w[q] = dinv[s[q]];
#pragma unroll
        for (int q = 0; q < 8; ++q)
            hv[q] = *(const unsigned short*)(h1 + (size_t)s[q] * 128 + lane * 2);
#pragma unroll
        for (int q = 0; q < 8; ++q) {
            float2v f = fp8x2_to_f32x2(hv[q]);
            ax += f.x * w[q];
            ay += f.y * w[q];
        }
    }
    if (n + 3 < s1) {
        int s[4];
        float w[4];
        unsigned short hv[4];
#pragma unroll
        for (int q = 0; q < 4; ++q) s[q] = adj[n + q];
#pragma unroll
        for (int q = 0; q < 4; ++q) w[q] = dinv[s[q]];
#pragma unroll
        for (int q = 0; q < 4; ++q)
            hv[q] = *(const unsigned short*)(h1 + (size_t)s[q] * 128 + lane * 2);
#pragma unroll
        for (int q = 0; q < 4; ++q) {
            float2v f = fp8x2_to_f32x2(hv[q]);
            ax += f.x * w[q];
            ay += f.y * w[q];
        }
        n += 4;
    }
    for (; n < s1; ++n) {
        int sa = adj[n];
        float wa = dinv[sa];
        float2v f = fp8x2_to_f32x2(*(const unsigned short*)(h1 + (size_t)sa * 128 + lane * 2));
        ax += f.x * wa;
        ay += f.y * wa;
    }
    float di = dinv[i];
    float self = di * di;
    float2v hi = fp8x2_to_f32x2(*(const unsigned short*)(h1 + (size_t)i * 128 + lane * 2));
    ax = ax * di + hi.x * self;
    ay = ay * di + hi.y * self;
    float2 bb = ((const float2*)b1)[lane];
    float2 xi = ((const float2*)(x + (size_t)i * FDIM))[lane];
    float rx = fmaxf(ax + bb.x, 0.f) + xi.x;
    float ry = fmaxf(ay + bb.y, 0.f) + xi.y;
    ((__half2*)(z + (size_t)i * FDIM))[lane] = __floats2half2_rn(rx, ry);
}

// ---- tiled GEMM2: h2 = z @ W2 (fp16 in, fp16 out, dense stride 40) ----
__launch_bounds__(256, 2)
__global__ void gemm2_tiled(const __half* __restrict__ z, const float* __restrict__ W2,
                            __half* __restrict__ h2, int N) {
    __shared__ float Ws[GK][64];
    __shared__ float zs[GK][132];
    int t = threadIdx.x;
    int tx = t & 15, ty = t >> 4;
    int i0 = blockIdx.x * 128;

    float acc[8][4];
#pragma unroll
    for (int a = 0; a < 8; ++a)
#pragma unroll
        for (int b = 0; b < 4; ++b) acc[a][b] = 0.f;

    for (int kb = 0; kb < FDIM / GK; ++kb) {
        __syncthreads();
        for (int p = t; p < GK * 64; p += 256) {
            int k = p >> 6, j = p & 63;
            Ws[k][j] = (j < 40) ? W2[(size_t)(kb * GK + k) * 40 + j] : 0.f;
        }
        int kq = (t & 3) * 8;
        int rb = t >> 2;
#pragma unroll
        for (int pass = 0; pass < 2; ++pass) {
            int r = pass * 64 + rb;
            int row = i0 + r;
            union { float4 v; __half2 hh[4]; } u;
            u.v = make_float4(0.f, 0.f, 0.f, 0.f);
            if (row < N) u.v = *(const float4*)(z + (size_t)row * FDIM + kb * GK + kq);
#pragma unroll
            for (int j = 0; j < 4; ++j) {
                float2 f = __half22float2(u.hh[j]);
                zs[kq + 2 * j][r] = f.x;
                zs[kq + 2 * j + 1][r] = f.y;
            }
        }
        __syncthreads();
#pragma unroll 4
        for (int k = 0; k < GK; ++k) {
            float4 a0 = *(const float4*)&zs[k][ty * 4];
            float4 a1 = *(const float4*)&zs[k][64 + ty * 4];
            float4 b0 = *(const float4*)&Ws[k][tx * 4];
            float av[8] = {a0.x, a0.y, a0.z, a0.w, a1.x, a1.y, a1.z, a1.w};
            float bv[4] = {b0.x, b0.y, b0.z, b0.w};
#pragma unroll
            for (int a = 0; a < 8; ++a)
#pragma unroll
                for (int b = 0; b < 4; ++b) acc[a][b] += av[a] * bv[b];
        }
    }
    if (tx < 10) {
#pragma unroll
        for (int g = 0; g < 2; ++g)
#pragma unroll
            for (int a = 0; a < 4; ++a) {
                int row = i0 + g * 64 + ty * 4 + a;
                if (row < N) {
                    int ri = g * 4 + a;
                    union { __half2 hh[2]; float2 f; } u;
                    u.hh[0] = __floats2half2_rn(acc[ri][0], acc[ri][1]);
                    u.hh[1] = __floats2half2_rn(acc[ri][2], acc[ri][3]);
                    *(float2*)(h2 + (size_t)row * 40 + tx * 4) = u.f;
                }
            }
    }
}

// y[i,:] = dinv[i]*(sum_s h2[s,:]*dinv[s] + h2[i,:]*dinv[i]) + b2
__global__ void agg2_kernel(const __half* __restrict__ h2, const int* __restrict__ rowstart,
                            const int* __restrict__ adj, const float* __restrict__ dinv,
                            const float* __restrict__ b2, float* __restrict__ y, int N) {
    int wave = threadIdx.x >> 6;
    int lane = threadIdx.x & 63;
    int i = blockIdx.x * 4 + wave;
    if (i >= N) return;
    int e = (lane >= 40) ? 2 : ((lane >= 20) ? 1 : 0);
    int f = lane - 20 * e;
    int s0 = rowstart[i], s1 = rowstart[i + 1];
    float ax = 0.f, ay = 0.f;
    if (lane < 60) {
        int n = s0 + e;
        for (; n + 9 < s1; n += 12) {
            int s[4];
            float w[4];
            float2 r[4];
#pragma unroll
            for (int q = 0; q < 4; ++q) s[q] = adj[n + 3 * q];
#pragma unroll
            for (int q = 0; q < 4; ++q) w[q] = dinv[s[q]];
#pragma unroll
            for (int q = 0; q < 4; ++q)
                r[q] = __half22float2(((const __half2*)(h2 + (size_t)s[q] * 40))[f]);
#pragma unroll
            for (int q = 0; q < 4; ++q) {
                ax += r[q].x * w[q];
                ay += r[q].y * w[q];
            }
        }
        for (; n < s1; n += 3) {
            int sa = adj[n];
            float wa = dinv[sa];
            float2 ra = __half22float2(((const __half2*)(h2 + (size_t)sa * 40))[f]);
            ax += ra.x * wa;
            ay += ra.y * wa;
        }
    }
    float sx = ax + __shfl(ax, lane + 20, 64) + __shfl(ax, lane + 40, 64);
    float sy = ay + __shfl(ay, lane + 20, 64) + __shfl(ay, lane + 40, 64);
    if (lane < 20) {
        float di = dinv[i];
        float2 hi = __half22float2(((const __half2*)(h2 + (size_t)i * 40))[lane]);
        float2 bb = ((const float2*)b2)[lane];
        float2 res;
        res.x = sx * di + hi.x * di * di + bb.x;
        res.y = sy * di + hi.y * di * di + bb.y;
        ((float2*)(y + (size_t)i * 40))[lane] = res;
    }
}

extern "C" void kernel_launch(void* const* d_in, const int* in_sizes, int n_in,
                              void* d_out, int out_size, void* d_ws, size_t ws_size,
                              hipStream_t stream) {
    const float* x  = (const float*)d_in[0];
    const int*   ei = (const int*)d_in[1];
    const float* W1 = (const float*)d_in[2];
    const float* b1 = (const float*)d_in[3];
    const float* W2 = (const float*)d_in[4];
    const float* b2 = (const float*)d_in[5];
    float* y = (float*)d_out;

    const int H = in_sizes[3];           // 128
    const int F = in_sizes[2] / H;       // 128
    const int N = in_sizes[0] / F;       // 50000
    const int E = in_sizes[1] / 2;       // 800000
    (void)H; (void)ws_size; (void)n_in; (void)out_size;

    const int nbk = (N + 255) >> 8;              // 196 buckets (<=256)
    const int nchunks = (E + CHUNK - 1) / CHUNK; // 391 (<=512)

    size_t off = 0;
    auto carve = [&](size_t bytes) -> void* {
        void* p = (char*)d_ws + off;
        off += (bytes + 255) & ~(size_t)255;
        return p;
    };
    int*           histT    = (int*)carve((size_t)nbk * nchunks * 4);
    int*           tot      = (int*)carve((size_t)nbk * 4);
    unsigned*      bkt      = (unsigned*)carve((size_t)E * 4);
    int*           rowstart = (int*)carve((size_t)(N + 1) * 4);
    float*         dinv     = (float*)carve((size_t)N * 4);
    int*           adj      = (int*)carve((size_t)E * 4);
    unsigned char* h1       = (unsigned char*)carve((size_t)N * 128);   // fp8 e4m3
    __half*        z        = (__half*)carve((size_t)N * FDIM * 2);
    __half*        h2       = (__half*)h1;   // h1 dead after agg1; N x 40 fp16 = 4 MB <= 6.4 MB

    hist_kernel<<<nchunks, 256, 0, stream>>>(ei + E, E, nchunks, nbk, histT);
    offsets_kernel<<<nbk, 512, 0, stream>>>(histT, nchunks, tot);
    scatter_kernel<<<nchunks, 256, 0, stream>>>(ei, E, nchunks, nbk, histT, tot, bkt);
    csr_kernel<<<nbk, 256, 0, stream>>>(tot, bkt, adj, rowstart, dinv, N, nbk, E);

    int nbt = (N + 127) / 128;
    gemm1_mfma<<<nbt, 256, 0, stream>>>(x, W1, h1, N);
    agg1_kernel<<<(N + 3) / 4, 256, 0, stream>>>(h1, rowstart, adj, dinv, x, b1, z, N);
    gemm2_tiled<<<nbt, 256, 0, stream>>>(z, W2, h2, N);
    agg2_kernel<<<(N + 3) / 4, 256, 0, stream>>>(h2, rowstart, adj, dinv, b2, y, N);
}

// Round 11
// 198.170 us; speedup vs baseline: 1.4960x; 1.0216x over previous
//
#include <hip/hip_runtime.h>
#include <hip/hip_fp16.h>

// 2-layer GCN, pull-based CSR aggregation. fp32 math; h1 stored fp8-e4m3
// (halves dominant agg1 gather traffic), z/h2 fp16.
// CSR build with ZERO global atomics (R5/R6: device atomics cap ~6/cyc):
//   K_hist -> K_offsets -> K_scatter -> K_csr  (LDS atomics + scans only)
// gemm1 = MFMA f16 (16x16x32, fp32 accum); fp8 epilogue via fp32 LDS tile
// with stride 132 (R10 post-mortem: byte-granular stride-128 LDS writes gave
// 1.05M bank conflicts; fp32 stride-132 is 2-way max = free).
// Then agg1(+bias,relu,residual) -> gemm2(vector) -> agg2 -> d_out.

#define FDIM 128
#define GK 32
#define CHUNK 2048   // edges per chunk; nchunks = ceil(E/CHUNK) must be <= 512

using half8   = __attribute__((ext_vector_type(8))) _Float16;
using float4v = __attribute__((ext_vector_type(4))) float;
using float2v = __attribute__((ext_vector_type(2))) float;

__device__ __forceinline__ float2v fp8x2_to_f32x2(unsigned short hv) {
    return __builtin_amdgcn_cvt_pk_f32_fp8((int)hv, false);
}

__global__ void hist_kernel(const int* __restrict__ dst, int E, int nchunks, int nbk,
                            int* __restrict__ histT) {
    __shared__ int hist[256];
    int j = blockIdx.x, t = threadIdx.x;
    hist[t] = 0;
    __syncthreads();
    int base = j * CHUNK;
#pragma unroll
    for (int k = 0; k < CHUNK / 256; ++k) {
        int e = base + k * 256 + t;
        if (e < E) atomicAdd(&hist[dst[e] >> 8], 1);
    }
    __syncthreads();
    if (t < nbk) histT[t * nchunks + j] = hist[t];
}

// per-bucket: exclusive scan of chunk counts (LOCAL, no base), bucket total out
__global__ void offsets_kernel(int* __restrict__ histT, int nchunks,
                               int* __restrict__ tot) {
    __shared__ int s[512];
    int b = blockIdx.x, t = threadIdx.x;
    int* row = histT + (size_t)b * nchunks;
    int v = (t < nchunks) ? row[t] : 0;
    s[t] = v;
    __syncthreads();
    for (int off = 1; off < 512; off <<= 1) {
        int tv = (t >= off) ? s[t - off] : 0;
        __syncthreads();
        s[t] += tv;
        __syncthreads();
    }
    if (t < nchunks) row[t] = s[t] - v;     // local exclusive offset
    if (t == 511) tot[b] = s[511];          // bucket total
}

__global__ void scatter_kernel(const int* __restrict__ ei, int E, int nchunks, int nbk,
                               const int* __restrict__ histT, const int* __restrict__ tot,
                               unsigned* __restrict__ bkt) {
    __shared__ int s[256];
    __shared__ int cur[256];
    int j = blockIdx.x, t = threadIdx.x;
    int v = (t < nbk) ? tot[t] : 0;
    s[t] = v;
    __syncthreads();
    for (int off = 1; off < 256; off <<= 1) {
        int tv = (t >= off) ? s[t - off] : 0;
        __syncthreads();
        s[t] += tv;
        __syncthreads();
    }
    if (t < nbk) cur[t] = (s[t] - v) + histT[t * nchunks + j];
    __syncthreads();
    int base = j * CHUNK;
#pragma unroll
    for (int k = 0; k < CHUNK / 256; ++k) {
        int e = base + k * 256 + t;
        if (e < E) {
            int src = ei[e];
            int d = ei[E + e];
            int pos = atomicAdd(&cur[d >> 8], 1);   // LDS atomic
            bkt[pos] = ((unsigned)(d & 255) << 24) | (unsigned)src;
        }
    }
}

__global__ void csr_kernel(const int* __restrict__ tot, const unsigned* __restrict__ bkt,
                           int* __restrict__ adj, int* __restrict__ rowstart,
                           float* __restrict__ dinv, int N, int nbk, int E) {
    __shared__ int sbuf[256];
    __shared__ int hist[256];
    __shared__ int cur[256];
    int b = blockIdx.x, t = threadIdx.x;
    int v = (t < nbk) ? tot[t] : 0;
    sbuf[t] = v;
    __syncthreads();
    for (int off = 1; off < 256; off <<= 1) {
        int tv = (t >= off) ? sbuf[t - off] : 0;
        __syncthreads();
        sbuf[t] += tv;
        __syncthreads();
    }
    int bb = sbuf[b] - ((b < nbk) ? tot[b] : 0);
    int nb = tot[b];
    __syncthreads();
    hist[t] = 0;
    __syncthreads();
    const unsigned* bk = bkt + bb;
    for (int e = t; e < nb; e += 256) atomicAdd(&hist[bk[e] >> 24], 1);
    __syncthreads();
    int h_t = hist[t];
    sbuf[t] = h_t;
    __syncthreads();
    for (int off = 1; off < 256; off <<= 1) {
        int vv = (t >= off) ? sbuf[t - off] : 0;
        __syncthreads();
        sbuf[t] += vv;
        __syncthreads();
    }
    int excl_t = sbuf[t] - h_t;
    int node = b * 256 + t;
    if (node < N) {
        rowstart[node] = bb + excl_t;
        dinv[node] = rsqrtf((float)(h_t + 1));   // +1 self-loop
    }
    if (b == 0 && t == 0) rowstart[N] = E;
    cur[t] = excl_t;
    __syncthreads();
    for (int e = t; e < nb; e += 256) {
        unsigned vv = bk[e];
        int pos = atomicAdd(&cur[vv >> 24], 1);   // LDS atomic
        adj[bb + pos] = (int)(vv & 0xFFFFFFu);    // src < 2^24
    }
}

// ---- MFMA GEMM1: h1 = fp16(x) @ fp16(W1), fp32 accum, fp8-e4m3 out ----
// 128-row tile per block, K=128 one shot. Shared buffer aliased:
//   staging: Xs[128*136] f16 (34816 B) + Wt[128*136] f16 (34816 B)
//   epilogue: T[128][132] f32 (67584 B) -- stride 132 => 2-way max conflicts
__launch_bounds__(256, 2)
__global__ void gemm1_mfma(const float* __restrict__ x, const float* __restrict__ W,
                           unsigned char* __restrict__ h, int N) {
    __shared__ __align__(16) unsigned char smem[69632];
    _Float16* Xs = (_Float16*)smem;
    _Float16* Wt = (_Float16*)(smem + 34816);
    int t = threadIdx.x;
    int i0 = blockIdx.x * 128;

    for (int p = t; p < 128 * 32; p += 256) {
        int row = p >> 5;
        int col4 = (p & 31) * 4;
        int grow = i0 + row;
        float4 v = make_float4(0.f, 0.f, 0.f, 0.f);
        if (grow < N) v = *(const float4*)(x + (size_t)grow * FDIM + col4);
        _Float16* d = &Xs[row * 136 + col4];
        d[0] = (_Float16)v.x;
        d[1] = (_Float16)v.y;
        d[2] = (_Float16)v.z;
        d[3] = (_Float16)v.w;
    }
    for (int p = t; p < 128 * 128; p += 256) {
        int k = p >> 7;
        int n = p & 127;
        Wt[n * 136 + k] = (_Float16)W[k * 128 + n];
    }
    __syncthreads();

    int lane = t & 63, w = t >> 6;
    int c = lane & 15, q = lane >> 4;
    int m0 = w * 32;

    float4v acc[2][8];
#pragma unroll
    for (int r = 0; r < 2; ++r)
#pragma unroll
        for (int nt = 0; nt < 8; ++nt) acc[r][nt] = (float4v)(0.f);

#pragma unroll
    for (int kk = 0; kk < 4; ++kk) {
        int k0 = kk * 32 + q * 8;
        half8 a0 = *(const half8*)&Xs[(m0 + c) * 136 + k0];
        half8 a1 = *(const half8*)&Xs[(m0 + 16 + c) * 136 + k0];
#pragma unroll
        for (int nt = 0; nt < 8; ++nt) {
            half8 bv = *(const half8*)&Wt[(nt * 16 + c) * 136 + k0];
            acc[0][nt] = __builtin_amdgcn_mfma_f32_16x16x32_f16(a0, bv, acc[0][nt], 0, 0, 0);
            acc[1][nt] = __builtin_amdgcn_mfma_f32_16x16x32_f16(a1, bv, acc[1][nt], 0, 0, 0);
        }
    }
    __syncthreads();   // staging dead; reuse smem as fp32 tile T[128][132]
    float* T = (float*)smem;
#pragma unroll
    for (int r = 0; r < 2; ++r)
#pragma unroll
        for (int reg = 0; reg < 4; ++reg) {
            int rl = m0 + r * 16 + q * 4 + reg;
#pragma unroll
            for (int nt = 0; nt < 8; ++nt)
                T[rl * 132 + nt * 16 + c] = acc[r][nt][reg];
        }
    __syncthreads();
    for (int p = t; p < 128 * 32; p += 256) {
        int row = p >> 5;
        int col4 = (p & 31) * 4;
        int grow = i0 + row;
        if (grow < N) {
            const float* src = &T[row * 132 + col4];
            int lo = __builtin_amdgcn_cvt_pk_fp8_f32(src[0], src[1], 0, false);
            int hi = __builtin_amdgcn_cvt_pk_fp8_f32(src[2], src[3], 0, false);
            unsigned word = ((unsigned)lo & 0xFFFFu) | (((unsigned)hi & 0xFFFFu) << 16);
            *(unsigned*)(h + (size_t)grow * 128 + col4) = word;
        }
    }
}

// z[i,:] = relu( dinv[i]*(sum_s h1[s,:]*dinv[s] + h1[i,:]*dinv[i]) + b1 ) + x[i,:]
// h1 is fp8-e4m3, 128 B/row; lane = 2 feats; 8 gathers in flight.
__global__ void agg1_kernel(const unsigned char* __restrict__ h1, const int* __restrict__ rowstart,
                            const int* __restrict__ adj, const float* __restrict__ dinv,
                            const float* __restrict__ x, const float* __restrict__ b1,
                            __half* __restrict__ z, int N) {
    int wave = threadIdx.x >> 6;
    int lane = threadIdx.x & 63;
    int i = blockIdx.x * 4 + wave;
    if (i >= N) return;
    int s0 = rowstart[i], s1 = rowstart[i + 1];
    float ax = 0.f, ay = 0.f;
    int n = s0;
    for (; n + 7 < s1; n += 8) {
        int s[8];
        float w[8];
        unsigned short hv[8];
#pragma unroll
        for (int q = 0; q < 8; ++q) s[q] = adj[n + q];
#pragma unroll
        for (int q = 0; q < 8; ++q) w[q] = dinv[s[q]];
#pragma unroll
        for (int q = 0; q < 8; ++q)
            hv[q] = *(const unsigned short*)(h1 + (size_t)s[q] * 128 + lane * 2);
#pragma unroll
        for (int q = 0; q < 8; ++q) {
            float2v f = fp8x2_to_f32x2(hv[q]);
            ax += f.x * w[q];
            ay += f.y * w[q];
        }
    }
    if (n + 3 < s1) {
        int s[4];
        float w[4];
        unsigned short hv[4];
#pragma unroll
        for (int q = 0; q < 4; ++q) s[q] = adj[n + q];
#pragma unroll
        for (int q = 0; q < 4; ++q) w[q] = dinv[s[q]];
#pragma unroll
        for (int q = 0; q < 4; ++q)
            hv[q] = *(const unsigned short*)(h1 + (size_t)s[q] * 128 + lane * 2);
#pragma unroll
        for (int q = 0; q < 4; ++q) {
            float2v f = fp8x2_to_f32x2(hv[q]);
            ax += f.x * w[q];
            ay += f.y * w[q];
        }
        n += 4;
    }
    for (; n < s1; ++n) {
        int sa = adj[n];
        float wa = dinv[sa];
        float2v f = fp8x2_to_f32x2(*(const unsigned short*)(h1 + (size_t)sa * 128 + lane * 2));
        ax += f.x * wa;
        ay += f.y * wa;
    }
    float di = dinv[i];
    float self = di * di;
    float2v hi = fp8x2_to_f32x2(*(const unsigned short*)(h1 + (size_t)i * 128 + lane * 2));
    ax = ax * di + hi.x * self;
    ay = ay * di + hi.y * self;
    float2 bb = ((const float2*)b1)[lane];
    float2 xi = ((const float2*)(x + (size_t)i * FDIM))[lane];
    float rx = fmaxf(ax + bb.x, 0.f) + xi.x;
    float ry = fmaxf(ay + bb.y, 0.f) + xi.y;
    ((__half2*)(z + (size_t)i * FDIM))[lane] = __floats2half2_rn(rx, ry);
}

// ---- tiled GEMM2: h2 = z @ W2 (fp16 in, fp16 out, dense stride 40) ----
__launch_bounds__(256, 2)
__global__ void gemm2_tiled(const __half* __restrict__ z, const float* __restrict__ W2,
                            __half* __restrict__ h2, int N) {
    __shared__ float Ws[GK][64];
    __shared__ float zs[GK][132];
    int t = threadIdx.x;
    int tx = t & 15, ty = t >> 4;
    int i0 = blockIdx.x * 128;

    float acc[8][4];
#pragma unroll
    for (int a = 0; a < 8; ++a)
#pragma unroll
        for (int b = 0; b < 4; ++b) acc[a][b] = 0.f;

    for (int kb = 0; kb < FDIM / GK; ++kb) {
        __syncthreads();
        for (int p = t; p < GK * 64; p += 256) {
            int k = p >> 6, j = p & 63;
            Ws[k][j] = (j < 40) ? W2[(size_t)(kb * GK + k) * 40 + j] : 0.f;
        }
        int kq = (t & 3) * 8;
        int rb = t >> 2;
#pragma unroll
        for (int pass = 0; pass < 2; ++pass) {
            int r = pass * 64 + rb;
            int row = i0 + r;
            union { float4 v; __half2 hh[4]; } u;
            u.v = make_float4(0.f, 0.f, 0.f, 0.f);
            if (row < N) u.v = *(const float4*)(z + (size_t)row * FDIM + kb * GK + kq);
#pragma unroll
            for (int j = 0; j < 4; ++j) {
                float2 f = __half22float2(u.hh[j]);
                zs[kq + 2 * j][r] = f.x;
                zs[kq + 2 * j + 1][r] = f.y;
            }
        }
        __syncthreads();
#pragma unroll 4
        for (int k = 0; k < GK; ++k) {
            float4 a0 = *(const float4*)&zs[k][ty * 4];
            float4 a1 = *(const float4*)&zs[k][64 + ty * 4];
            float4 b0 = *(const float4*)&Ws[k][tx * 4];
            float av[8] = {a0.x, a0.y, a0.z, a0.w, a1.x, a1.y, a1.z, a1.w};
            float bv[4] = {b0.x, b0.y, b0.z, b0.w};
#pragma unroll
            for (int a = 0; a < 8; ++a)
#pragma unroll
                for (int b = 0; b < 4; ++b) acc[a][b] += av[a] * bv[b];
        }
    }
    if (tx < 10) {
#pragma unroll
        for (int g = 0; g < 2; ++g)
#pragma unroll
            for (int a = 0; a < 4; ++a) {
                int row = i0 + g * 64 + ty * 4 + a;
                if (row < N) {
                    int ri = g * 4 + a;
                    union { __half2 hh[2]; float2 f; } u;
                    u.hh[0] = __floats2half2_rn(acc[ri][0], acc[ri][1]);
                    u.hh[1] = __floats2half2_rn(acc[ri][2], acc[ri][3]);
                    *(float2*)(h2 + (size_t)row * 40 + tx * 4) = u.f;
                }
            }
    }
}

// y[i,:] = dinv[i]*(sum_s h2[s,:]*dinv[s] + h2[i,:]*dinv[i]) + b2
__global__ void agg2_kernel(const __half* __restrict__ h2, const int* __restrict__ rowstart,
                            const int* __restrict__ adj, const float* __restrict__ dinv,
                            const float* __restrict__ b2, float* __restrict__ y, int N) {
    int wave = threadIdx.x >> 6;
    int lane = threadIdx.x & 63;
    int i = blockIdx.x * 4 + wave;
    if (i >= N) return;
    int e = (lane >= 40) ? 2 : ((lane >= 20) ? 1 : 0);
    int f = lane - 20 * e;
    int s0 = rowstart[i], s1 = rowstart[i + 1];
    float ax = 0.f, ay = 0.f;
    if (lane < 60) {
        int n = s0 + e;
        for (; n + 9 < s1; n += 12) {
            int s[4];
            float w[4];
            float2 r[4];
#pragma unroll
            for (int q = 0; q < 4; ++q) s[q] = adj[n + 3 * q];
#pragma unroll
            for (int q = 0; q < 4; ++q) w[q] = dinv[s[q]];
#pragma unroll
            for (int q = 0; q < 4; ++q)
                r[q] = __half22float2(((const __half2*)(h2 + (size_t)s[q] * 40))[f]);
#pragma unroll
            for (int q = 0; q < 4; ++q) {
                ax += r[q].x * w[q];
                ay += r[q].y * w[q];
            }
        }
        for (; n < s1; n += 3) {
            int sa = adj[n];
            float wa = dinv[sa];
            float2 ra = __half22float2(((const __half2*)(h2 + (size_t)sa * 40))[f]);
            ax += ra.x * wa;
            ay += ra.y * wa;
        }
    }
    float sx = ax + __shfl(ax, lane + 20, 64) + __shfl(ax, lane + 40, 64);
    float sy = ay + __shfl(ay, lane + 20, 64) + __shfl(ay, lane + 40, 64);
    if (lane < 20) {
        float di = dinv[i];
        float2 hi = __half22float2(((const __half2*)(h2 + (size_t)i * 40))[lane]);
        float2 bb = ((const float2*)b2)[lane];
        float2 res;
        res.x = sx * di + hi.x * di * di + bb.x;
        res.y = sy * di + hi.y * di * di + bb.y;
        ((float2*)(y + (size_t)i * 40))[lane] = res;
    }
}

extern "C" void kernel_launch(void* const* d_in, const int* in_sizes, int n_in,
                              void* d_out, int out_size, void* d_ws, size_t ws_size,
                              hipStream_t stream) {
    const float* x  = (const float*)d_in[0];
    const int*   ei = (const int*)d_in[1];
    const float* W1 = (const float*)d_in[2];
    const float* b1 = (const float*)d_in[3];
    const float* W2 = (const float*)d_in[4];
    const float* b2 = (const float*)d_in[5];
    float* y = (float*)d_out;

    const int H = in_sizes[3];           // 128
    const int F = in_sizes[2] / H;       // 128
    const int N = in_sizes[0] / F;       // 50000
    const int E = in_sizes[1] / 2;       // 800000
    (void)H; (void)ws_size; (void)n_in; (void)out_size;

    const int nbk = (N + 255) >> 8;              // 196 buckets (<=256)
    const int nchunks = (E + CHUNK - 1) / CHUNK; // 391 (<=512)

    size_t off = 0;
    auto carve = [&](size_t bytes) -> void* {
        void* p = (char*)d_ws + off;
        off += (bytes + 255) & ~(size_t)255;
        return p;
    };
    int*           histT    = (int*)carve((size_t)nbk * nchunks * 4);
    int*           tot      = (int*)carve((size_t)nbk * 4);
    unsigned*      bkt      = (unsigned*)carve((size_t)E * 4);
    int*           rowstart = (int*)carve((size_t)(N + 1) * 4);
    float*         dinv     = (float*)carve((size_t)N * 4);
    int*           adj      = (int*)carve((size_t)E * 4);
    unsigned char* h1       = (unsigned char*)carve((size_t)N * 128);   // fp8 e4m3
    __half*        z        = (__half*)carve((size_t)N * FDIM * 2);
    __half*        h2       = (__half*)h1;   // h1 dead after agg1; N x 40 fp16 fits

    hist_kernel<<<nchunks, 256, 0, stream>>>(ei + E, E, nchunks, nbk, histT);
    offsets_kernel<<<nbk, 512, 0, stream>>>(histT, nchunks, tot);
    scatter_kernel<<<nchunks, 256, 0, stream>>>(ei, E, nchunks, nbk, histT, tot, bkt);
    csr_kernel<<<nbk, 256, 0, stream>>>(tot, bkt, adj, rowstart, dinv, N, nbk, E);

    int nbt = (N + 127) / 128;
    gemm1_mfma<<<nbt, 256, 0, stream>>>(x, W1, h1, N);
    agg1_kernel<<<(N + 3) / 4, 256, 0, stream>>>(h1, rowstart, adj, dinv, x, b1, z, N);
    gemm2_tiled<<<nbt, 256, 0, stream>>>(z, W2, h2, N);
    agg2_kernel<<<(N + 3) / 4, 256, 0, stream>>>(h2, rowstart, adj, dinv, b2, y, N);
}